// Round 9
// baseline (1120.740 us; speedup 1.0000x reference)
//
#include <hip/hip_runtime.h>
#include <math.h>

// S4D block, MI355X round 9: 512-thread scan blocks (32 waves/CU), chunk=16.
// B=8, H=256, T=8192, N=16 complex states.

#define TN 8192
#define HN 256
#define BN 8
#define NS 16

typedef __bf16 bf16x8 __attribute__((ext_vector_type(8)));
typedef __bf16 bf16x4 __attribute__((ext_vector_type(4)));
typedef __bf16 bf16x2 __attribute__((ext_vector_type(2)));
typedef float  f32x4  __attribute__((ext_vector_type(4)));

__device__ __forceinline__ float gelu_f(float v) {
    return 0.5f * v * (1.f + erff(v * 0.70710678118654752440f));
}
__device__ __forceinline__ float sigm_f(float v) {
    return 1.f / (1.f + expf(-v));
}

// ---------------- SSM constant prep: store dt*A + 2*Cmod ----------------
__global__ void prep_kernel(const float* __restrict__ log_dt,
                            const float* __restrict__ C_re,
                            const float* __restrict__ C_im,
                            const float* __restrict__ log_A_real,
                            const float* __restrict__ A_imag,
                            float* __restrict__ P)
{
    int i = blockIdx.x * 64 + threadIdx.x;   // 0..4095
    int h = i >> 4;
    float dt = expf(log_dt[h]);
    float Ar = -expf(log_A_real[i]);
    float Ai = A_imag[i];
    float dar = Ar * dt, dai = Ai * dt;
    float er = expf(dar);
    float ar = er * cosf(dai);
    float ai = er * sinf(dai);
    float Er = ar - 1.f, Ei = ai;
    float inv = 1.f / (Ar * Ar + Ai * Ai);
    float Fr = (Er * Ar + Ei * Ai) * inv;
    float Fi = (Ei * Ar - Er * Ai) * inv;
    float cr = C_re[i] * Fr - C_im[i] * Fi;
    float ci = C_re[i] * Fi + C_im[i] * Fr;
    P[i]           = dar;
    P[4096 + i]    = dai;
    P[2*4096 + i]  = 2.f * cr;
    P[3*4096 + i]  = 2.f * ci;
}

// ---------------- weight prep: fp32 -> bf16, tiled+swizzled LDS image ----------------
__global__ void prep_w_kernel(const float* __restrict__ W, __bf16* __restrict__ Wp,
                              int K, int glu)
{
    int id = blockIdx.x * 256 + threadIdx.x;
    int nK = K >> 6;
    int c = id >> 10, r = (id >> 3) & 127, s = id & 7;
    int mt = c / nK, kt = c - mt * nK;
    int R = mt * 128 + r;
    int row = glu ? ((R & 1) ? (R >> 1) + 256 : (R >> 1)) : R;
    int k = kt * 64 + ((s ^ (r & 7)) << 3);
    const float* src = W + (size_t)row * K + k;
    __bf16 o[8];
    #pragma unroll
    for (int j = 0; j < 8; ++j) o[j] = (__bf16)src[j];
    *(uint4*)(Wp + (size_t)id * 8) = *(uint4*)o;
}

// ---------------- LN stats finalize ----------------
__global__ __launch_bounds__(256) void ln_fin_kernel(const float* __restrict__ s,
                                                     const float* __restrict__ ss,
                                                     float* __restrict__ mu,
                                                     float* __restrict__ rs)
{
    int i = blockIdx.x * 256 + threadIdx.x;   // 0..65535
    float m = s[i] * (1.f / 256.f);
    mu[i] = m;
    rs[i] = rsqrtf(ss[i] * (1.f / 256.f) - m * m + 1e-5f);
}

// ---------------- transpose [B][H][T] (f32 or bf16) -> [B][T][H] bf16, optional LN stats ----------------
template<typename TI, bool STATS>
__global__ __launch_bounds__(256) void transpose_kernel(const TI* __restrict__ in,
                                                        __bf16* __restrict__ out,
                                                        float* __restrict__ sAcc,
                                                        float* __restrict__ ssAcc)
{
    __shared__ float tile[64][65];
    int b = blockIdx.z, h0 = blockIdx.y * 64, t0 = blockIdx.x * 64;
    int tid = threadIdx.x;
    int hl = tid >> 2, pr = tid & 3;
    const TI* src = in + ((size_t)(b * HN + h0 + hl)) * TN + t0 + pr * 16;
    if constexpr (sizeof(TI) == 4) {
        #pragma unroll
        for (int j = 0; j < 4; ++j) {
            float4 v = *(const float4*)((const float*)src + j * 4);
            *(float4*)&tile[hl][pr * 16 + j * 4] = v;
        }
    } else {
        #pragma unroll
        for (int p = 0; p < 2; ++p) {
            bf16x8 v = *(const bf16x8*)((const __bf16*)src + p * 8);
            #pragma unroll
            for (int j = 0; j < 8; ++j) tile[hl][pr * 16 + p * 8 + j] = (float)v[j];
        }
    }
    __syncthreads();
    int tl = tid >> 2;
    __bf16 o[16];
    #pragma unroll
    for (int j = 0; j < 16; ++j) o[j] = (__bf16)tile[pr * 16 + j][tl];
    __bf16* dst = out + ((size_t)(b * TN + t0 + tl)) * HN + h0 + pr * 16;
    *(uint4*)dst = *(uint4*)&o[0];
    *(uint4*)(dst + 8) = *(uint4*)&o[8];
    if constexpr (STATS) {
        if (tid < 64) {
            float s = 0.f, ss = 0.f;
            #pragma unroll 8
            for (int hh = 0; hh < 64; ++hh) {
                float v = tile[hh][tid];
                s += v; ss += v * v;
            }
            atomicAdd(&sAcc[b * TN + t0 + tid], s);
            atomicAdd(&ssAcc[b * TN + t0 + tid], ss);
        }
    }
}

// ---------------- S4D scan: 512 threads, chunk=16 elems, 16 states/thread ----------------
// KS over 64 lanes (decay a^(16*2^k)) + 8-wave combine (a^1024). 32 waves/CU.
__global__ __launch_bounds__(512, 8) void scan_kernel(const float* __restrict__ X,
                                                      const float* __restrict__ mu,
                                                      const float* __restrict__ rs,
                                                      const float* __restrict__ g1,
                                                      const float* __restrict__ b1,
                                                      const float* __restrict__ Dp,
                                                      const float* __restrict__ P,
                                                      __bf16* __restrict__ GU)
{
    __shared__ float ylds[512 * 17];      // 34816B
    __shared__ float astab[16][2];
    __shared__ float c2tab[16][2];
    __shared__ float ksd[7][16][2];       // a^(16*2^k), k=0..6 (k=6 -> a^1024)
    __shared__ float wtot[8][16][2];
    int row = blockIdx.x;
    int b = row >> 8, h = row & 255;
    int tid = threadIdx.x;
    int w = tid >> 6, l = tid & 63;

    float gh = g1[h], bh = b1[h], dh = Dp[h];
    const float* xrow = X + (size_t)(b * HN + h) * TN;
    const float* mup = mu + b * TN;
    const float* rsp = rs + b * TN;

    // ---- tables, spread over threads ----
    if (tid < 112) {
        int k = tid >> 4, n = tid & 15;
        float dar = P[h * NS + n], dai = P[4096 + h * NS + n];
        float m = (float)(16 << k);
        float er = expf(m * dar), ph = m * dai;
        ksd[k][n][0] = er * cosf(ph);
        ksd[k][n][1] = er * sinf(ph);
    } else if (tid < 128) {
        int n = tid & 15;
        float dar = P[h * NS + n], dai = P[4096 + h * NS + n];
        float e1 = expf(dar);
        astab[n][0] = e1 * cosf(dai);
        astab[n][1] = e1 * sinf(dai);
        c2tab[n][0] = P[2*4096 + h * NS + n];
        c2tab[n][1] = P[3*4096 + h * NS + n];
    }

    // ---- stage row + inline LN1 ----
    #pragma unroll 2
    for (int s = 0; s < 4; ++s) {
        int t = (s * 512 + tid) * 4;
        float4 xv = *(const float4*)(xrow + t);
        float4 m4 = *(const float4*)(mup + t);
        float4 r4 = *(const float4*)(rsp + t);
        float* dst = &ylds[(t >> 4) * 17 + (t & 15)];
        dst[0] = fmaf((xv.x - m4.x) * r4.x, gh, bh);
        dst[1] = fmaf((xv.y - m4.y) * r4.y, gh, bh);
        dst[2] = fmaf((xv.z - m4.z) * r4.z, gh, bh);
        dst[3] = fmaf((xv.w - m4.w) * r4.w, gh, bh);
    }
    __syncthreads();

    float ar_[16], ai_[16];
    #pragma unroll
    for (int n = 0; n < 16; ++n) { ar_[n] = astab[n][0]; ai_[n] = astab[n][1]; }

    // ---- pass A: chunk summary (16 elems) ----
    float sr[16], si[16];
    #pragma unroll
    for (int n = 0; n < 16; ++n) { sr[n] = 0.f; si[n] = 0.f; }
    const float* yc = &ylds[tid * 17];
    #pragma unroll 1
    for (int g = 0; g < 2; ++g) {
        float yv[8];
        #pragma unroll
        for (int e = 0; e < 8; ++e) yv[e] = yc[g * 8 + e];
        #pragma unroll
        for (int e = 0; e < 8; ++e) {
            float y = yv[e];
            #pragma unroll
            for (int n = 0; n < 16; ++n) {
                float nr = fmaf(ar_[n], sr[n], fmaf(-ai_[n], si[n], y));
                si[n] = fmaf(ar_[n], si[n], ai_[n] * sr[n]);
                sr[n] = nr;
            }
        }
    }

    // ---- Kogge-Stone over 64 chunks in wave ----
    #pragma unroll
    for (int k = 0; k < 6; ++k) {
        int d = 1 << k;
        #pragma unroll
        for (int n = 0; n < 16; ++n) {
            float qpr = __shfl_up(sr[n], (unsigned)d, 64);
            float qpi = __shfl_up(si[n], (unsigned)d, 64);
            if (l >= d) {
                float pdr = ksd[k][n][0], pdi = ksd[k][n][1];
                sr[n] = fmaf(pdr, qpr, fmaf(-pdi, qpi, sr[n]));
                si[n] = fmaf(pdr, qpi, fmaf(pdi, qpr, si[n]));
            }
        }
    }
    if (l == 63) {
        #pragma unroll
        for (int n = 0; n < 16; ++n) { wtot[w][n][0] = sr[n]; wtot[w][n][1] = si[n]; }
    }
    __syncthreads();

    // ---- s_init per chunk ----
    #pragma unroll
    for (int n = 0; n < 16; ++n) {
        float Lr = __shfl_up(sr[n], 1u, 64);
        float Li = __shfl_up(si[n], 1u, 64);
        if (l == 0) { Lr = 0.f; Li = 0.f; }
        float Sr = 0.f, Si = 0.f;
        float d6r = ksd[6][n][0], d6i = ksd[6][n][1];
        for (int v = 0; v < w; ++v) {
            float tr = fmaf(d6r, Sr, fmaf(-d6i, Si, wtot[v][n][0]));
            float ti = fmaf(d6r, Si, fmaf(d6i, Sr, wtot[v][n][1]));
            Sr = tr; Si = ti;
        }
        float qr = 1.f, qi = 0.f;
        #pragma unroll
        for (int k = 0; k < 6; ++k) {
            if ((l >> k) & 1) {
                float kr = ksd[k][n][0], ki = ksd[k][n][1];
                float t2 = qr * kr - qi * ki;
                qi = fmaf(qr, ki, qi * kr);
                qr = t2;
            }
        }
        sr[n] = fmaf(qr, Sr, fmaf(-qi, Si, Lr));
        si[n] = fmaf(qr, Si, fmaf(qi, Sr, Li));
    }

    float c2r_[16], c2i_[16];
    #pragma unroll
    for (int n = 0; n < 16; ++n) { c2r_[n] = c2tab[n][0]; c2i_[n] = c2tab[n][1]; }

    // ---- pass B: seeded rescan, emit gelu(u) in place ----
    float* yw = &ylds[tid * 17];
    #pragma unroll 1
    for (int g = 0; g < 2; ++g) {
        float yv[8];
        #pragma unroll
        for (int e = 0; e < 8; ++e) yv[e] = yw[g * 8 + e];
        #pragma unroll
        for (int e = 0; e < 8; ++e) {
            float y = yv[e];
            float u = dh * y;
            #pragma unroll
            for (int n = 0; n < 16; ++n) {
                float nr = fmaf(ar_[n], sr[n], fmaf(-ai_[n], si[n], y));
                si[n] = fmaf(ar_[n], si[n], ai_[n] * sr[n]);
                sr[n] = nr;
                u = fmaf(c2r_[n], nr, fmaf(-c2i_[n], si[n], u));
            }
            yv[e] = gelu_f(u);
        }
        #pragma unroll
        for (int e = 0; e < 8; ++e) yw[g * 8 + e] = yv[e];
    }
    __syncthreads();

    // ---- coalesced bf16 write ----
    __bf16* gout = GU + (size_t)(b * HN + h) * TN;
    #pragma unroll 2
    for (int s = 0; s < 4; ++s) {
        int t = (s * 512 + tid) * 4;
        const float* src = &ylds[(t >> 4) * 17 + (t & 15)];
        bf16x4 ov;
        ov[0] = (__bf16)src[0]; ov[1] = (__bf16)src[1];
        ov[2] = (__bf16)src[2]; ov[3] = (__bf16)src[3];
        *(bf16x4*)(gout + t) = ov;
    }
}

// ---------------- MFMA conv1x1 GEMM, channels-last, 1D XCD-swizzled grid ----------------
// OMODE 0: bf16 out [B][T][H]
// OMODE 1: bf16 A [B][T][H] = GLU + bf16 resB, + LN2 partial stats (atomics)
// OMODE 2: fp32 out [B][H][T] += bf16 resB (cl), LDS-transposed store
template<int K, int NTY, bool GLU, bool CONCAT, bool LNIN, bool GELUOUT, int OMODE>
__global__ __launch_bounds__(256) void gemm_cl_kernel(
    const __bf16* __restrict__ B0, const __bf16* __restrict__ B1,
    const __bf16* __restrict__ BA,
    const __bf16* __restrict__ Wp, const float* __restrict__ bias,
    const float* __restrict__ mu, const float* __restrict__ rsd,
    const float* __restrict__ lng, const float* __restrict__ lnb,
    const __bf16* __restrict__ resB,
    float* __restrict__ sAcc, float* __restrict__ ssAcc,
    float* __restrict__ outF, __bf16* __restrict__ outB)
{
    constexpr int nK = K / 64;
    constexpr int LDSSZ = (OMODE != 0) ? 34816 : 32768;
    __shared__ __align__(16) char lds[LDSSZ];
    char* sA = lds;
    char* sB = lds + 16384;
    int tid = threadIdx.x;
    int w = tid >> 6, wr = w >> 1, wc = w & 1;

    int f = blockIdx.x;
    int r8 = f & 7, m = f >> 3;
    int by = m % NTY;
    int c = (m / NTY) * 8 + r8;
    int b = c >> 6;
    int t0 = (c & 63) * 128;

    int lane = tid & 63;
    int lr = tid & 15, lg = (tid >> 4) & 3;
    int rl = lane >> 3, sl = lane & 7;

    f32x4 acc[4][4];
    #pragma unroll
    for (int i = 0; i < 4; ++i)
        #pragma unroll
        for (int j = 0; j < 4; ++j) acc[i][j] = (f32x4){0.f, 0.f, 0.f, 0.f};

    for (int kt = 0; kt < nK; ++kt) {
        {
            const char* asrc = (const char*)Wp + (((size_t)by * nK + kt) << 14)
                               + w * 4096 + lane * 16;
            char* adst = sA + w * 4096;
            #pragma unroll
            for (int i = 0; i < 4; ++i)
                __builtin_amdgcn_global_load_lds(
                    (const __attribute__((address_space(1))) void*)(asrc + i * 1024),
                    (__attribute__((address_space(3))) void*)(adst + i * 1024), 16, 0, 0);
        }
        if constexpr (!LNIN) {
            int kg = kt * 64;
            const __bf16* base = (CONCAT && kg >= 256) ? B1 : B0;
            int kloc = (CONCAT && kg >= 256) ? kg - 256 : kg;
            #pragma unroll
            for (int i = 0; i < 4; ++i) {
                int rb = w * 32 + i * 8 + rl;
                const char* gs = (const char*)(base + (((size_t)(b * TN + t0 + rb)) << 8) + kloc)
                                 + ((sl ^ rl) << 4);
                __builtin_amdgcn_global_load_lds(
                    (const __attribute__((address_space(1))) void*)gs,
                    (__attribute__((address_space(3))) void*)(sB + w * 4096 + i * 1024), 16, 0, 0);
            }
        } else {
            #pragma unroll
            for (int i = 0; i < 8; ++i) {
                int q = i * 256 + tid;
                int rq = q >> 4, qs = q & 15;
                int t = t0 + rq;
                bf16x4 av = *(const bf16x4*)(BA + (((size_t)(b * TN + t)) << 8) + kt * 64 + qs * 4);
                float m_ = mu[b * TN + t], rr = rsd[b * TN + t];
                float4 g4 = *(const float4*)(lng + kt * 64 + qs * 4);
                float4 b4 = *(const float4*)(lnb + kt * 64 + qs * 4);
                __bf16 o[4];
                o[0] = (__bf16)fmaf(((float)av[0] - m_) * rr, g4.x, b4.x);
                o[1] = (__bf16)fmaf(((float)av[1] - m_) * rr, g4.y, b4.y);
                o[2] = (__bf16)fmaf(((float)av[2] - m_) * rr, g4.z, b4.z);
                o[3] = (__bf16)fmaf(((float)av[3] - m_) * rr, g4.w, b4.w);
                int off = rq * 128 + ((((qs >> 1) ^ (rq & 7))) << 4) + (qs & 1) * 8;
                *(uint2*)(sB + off) = *(uint2*)o;
            }
        }
        __syncthreads();

        const char* aB = sA + (wr * 64 + lr) * 128;
        const char* bB = sB + (wc * 64 + lr) * 128;
        int swz = (lr & 7) << 4;
        #pragma unroll
        for (int ks = 0; ks < 2; ++ks) {
            int ko = (ks * 64 + lg * 16) ^ swz;
            bf16x8 af[4], bfr[4];
            #pragma unroll
            for (int ff = 0; ff < 4; ++ff) af[ff]  = *(const bf16x8*)(aB + ff * 2048 + ko);
            #pragma unroll
            for (int ff = 0; ff < 4; ++ff) bfr[ff] = *(const bf16x8*)(bB + ff * 2048 + ko);
            #pragma unroll
            for (int fm = 0; fm < 4; ++fm)
                #pragma unroll
                for (int fn = 0; fn < 4; ++fn)
                    acc[fm][fn] = __builtin_amdgcn_mfma_f32_16x16x32_bf16(
                        af[fm], bfr[fn], acc[fm][fn], 0, 0, 0);
        }
        __syncthreads();
    }

    int tcb = t0 + wc * 64 + lr;
    int mrow0 = by * 128 + wr * 64 + lg * 4;

    if constexpr (OMODE == 1) {
        float* tile = (float*)lds;
        #pragma unroll
        for (int fm = 0; fm < 4; ++fm) {
            int R0 = mrow0 + fm * 16;
            int c_ = R0 >> 1;
            int cloc = c_ - by * 64;
            #pragma unroll
            for (int fn = 0; fn < 4; ++fn) {
                f32x4 v = acc[fm][fn];
                float a0 = v[0] + bias[c_],     g0 = v[1] + bias[c_ + 256];
                float a1 = v[2] + bias[c_ + 1], g1 = v[3] + bias[c_ + 257];
                float o0 = a0 * sigm_f(g0), o1 = a1 * sigm_f(g1);
                int tl = wc * 64 + lr + fn * 16;
                *(float2*)&tile[tl * 68 + cloc] = make_float2(o0, o1);
            }
        }
        __syncthreads();
        #pragma unroll
        for (int it = 0; it < 8; ++it) {
            int fid = it * 256 + tid;
            int tl = fid >> 4, fc = (fid & 15) << 2;
            size_t go = (((size_t)(b * TN + t0 + tl)) << 8) + by * 64 + fc;
            float4 v = *(const float4*)&tile[tl * 68 + fc];
            bf16x4 xr = *(const bf16x4*)(resB + go);
            v.x += (float)xr[0]; v.y += (float)xr[1];
            v.z += (float)xr[2]; v.w += (float)xr[3];
            *(float4*)&tile[tl * 68 + fc] = v;
            bf16x4 ov;
            ov[0] = (__bf16)v.x; ov[1] = (__bf16)v.y;
            ov[2] = (__bf16)v.z; ov[3] = (__bf16)v.w;
            *(bf16x4*)(outB + go) = ov;
        }
        __syncthreads();
        if (tid < 128) {
            const float* rowp = &tile[tid * 68];
            float s = 0.f, ss = 0.f;
            #pragma unroll 8
            for (int cc = 0; cc < 64; ++cc) {
                float v = rowp[cc];
                s += v; ss += v * v;
            }
            atomicAdd(&sAcc[b * TN + t0 + tid], s);
            atomicAdd(&ssAcc[b * TN + t0 + tid], ss);
        }
    } else if constexpr (OMODE == 2) {
        float* tile = (float*)lds;
        #pragma unroll
        for (int ht = 0; ht < 2; ++ht) {
            if (wc == ht) {
                #pragma unroll
                for (int fm = 0; fm < 4; ++fm) {
                    int R0 = mrow0 + fm * 16;
                    int mloc = R0 - by * 128;
                    #pragma unroll
                    for (int fn = 0; fn < 4; ++fn) {
                        int t = tcb + fn * 16;
                        f32x4 v = acc[fm][fn];
                        bf16x4 rv = *(const bf16x4*)(resB + (((size_t)(b * TN + t)) << 8) + R0);
                        int tloc = lr + fn * 16;
                        tile[(mloc + 0) * 68 + tloc] = v[0] + bias[R0 + 0] + (float)rv[0];
                        tile[(mloc + 1) * 68 + tloc] = v[1] + bias[R0 + 1] + (float)rv[1];
                        tile[(mloc + 2) * 68 + tloc] = v[2] + bias[R0 + 2] + (float)rv[2];
                        tile[(mloc + 3) * 68 + tloc] = v[3] + bias[R0 + 3] + (float)rv[3];
                    }
                }
            }
            __syncthreads();
            #pragma unroll
            for (int it = 0; it < 8; ++it) {
                int fid = it * 256 + tid;
                int mm = fid >> 4, fc = (fid & 15) << 2;
                float4 v = *(const float4*)&tile[mm * 68 + fc];
                *(float4*)(outF + ((size_t)(b * HN + by * 128 + mm)) * TN + t0 + ht * 64 + fc) = v;
            }
            __syncthreads();
        }
    } else {
        #pragma unroll
        for (int fm = 0; fm < 4; ++fm) {
            int R0 = mrow0 + fm * 16;
            #pragma unroll
            for (int fn = 0; fn < 4; ++fn) {
                int t = tcb + fn * 16;
                f32x4 v = acc[fm][fn];
                size_t rowoff = ((size_t)(b * TN + t)) << 8;
                if constexpr (GLU) {
                    int c_ = R0 >> 1;
                    float a0 = v[0] + bias[c_],     g0 = v[1] + bias[c_ + 256];
                    float a1 = v[2] + bias[c_ + 1], g1 = v[3] + bias[c_ + 257];
                    float o0 = a0 * sigm_f(g0), o1 = a1 * sigm_f(g1);
                    if constexpr (GELUOUT) { o0 = gelu_f(o0); o1 = gelu_f(o1); }
                    bf16x2 ov; ov[0] = (__bf16)o0; ov[1] = (__bf16)o1;
                    *(bf16x2*)(outB + rowoff + c_) = ov;
                } else {
                    float vv[4];
                    #pragma unroll
                    for (int j = 0; j < 4; ++j) vv[j] = v[j] + bias[R0 + j];
                    if constexpr (GELUOUT) {
                        #pragma unroll
                        for (int j = 0; j < 4; ++j) vv[j] = gelu_f(vv[j]);
                    }
                    bf16x4 ov;
                    #pragma unroll
                    for (int j = 0; j < 4; ++j) ov[j] = (__bf16)vv[j];
                    *(bf16x4*)(outB + rowoff + R0) = ov;
                }
            }
        }
    }
}

extern "C" void kernel_launch(void* const* d_in, const int* in_sizes, int n_in,
                              void* d_out, int out_size, void* d_ws, size_t ws_size,
                              hipStream_t stream)
{
    (void)in_sizes; (void)n_in; (void)out_size; (void)ws_size;
    const float* x      = (const float*)d_in[0];
    const float* log_dt = (const float*)d_in[1];
    const float* C_re   = (const float*)d_in[2];
    const float* C_im   = (const float*)d_in[3];
    const float* logAr  = (const float*)d_in[4];
    const float* A_im   = (const float*)d_in[5];
    const float* Dp     = (const float*)d_in[6];
    const float* outW   = (const float*)d_in[7];
    const float* outB   = (const float*)d_in[8];
    const float* ln1g   = (const float*)d_in[9];
    const float* ln1b   = (const float*)d_in[10];
    const float* lin1W  = (const float*)d_in[11];
    const float* lin1b  = (const float*)d_in[12];
    const float* gluW   = (const float*)d_in[13];
    const float* glub   = (const float*)d_in[14];
    const float* ln2g   = (const float*)d_in[15];
    const float* ln2b   = (const float*)d_in[16];
    const float* ff2aW  = (const float*)d_in[17];
    const float* ff2ab  = (const float*)d_in[18];
    const float* ff2bW  = (const float*)d_in[19];
    const float* ff2bb  = (const float*)d_in[20];
    float* out = (float*)d_out;

    char* ws = (char*)d_ws;
    const size_t MB = 1u << 20;
    float*  P    = (float*)(ws);
    float*  mu1  = (float*)(ws + 0x40000);
    float*  rs1  = (float*)(ws + 0x80000);
    float*  mu2  = (float*)(ws + 0xC0000);
    float*  rs2  = (float*)(ws + 0x100000);
    __bf16* WpO  = (__bf16*)(ws + 0x140000);
    __bf16* WpL  = (__bf16*)(ws + 0x180000);
    __bf16* WpG  = (__bf16*)(ws + 0x1A0000);
    __bf16* WpA  = (__bf16*)(ws + 0x220000);
    __bf16* WpB  = (__bf16*)(ws + 0x240000);
    float*  s1   = (float*)(ws + 0x280000);
    float*  ss1  = (float*)(ws + 0x2C0000);
    float*  s2   = (float*)(ws + 0x300000);
    float*  ss2  = (float*)(ws + 0x340000);
    __bf16* x_cl = (__bf16*)(ws + 4 * MB);     // 32MB [B][T][H] bf16
    char*   slB  = ws + 36 * MB;               // 32MB
    char*   slC  = ws + 68 * MB;               // 32MB

    // zero stats accumulators (s1,ss1,s2,ss2 contiguous 1MB)
    hipMemsetAsync(ws + 0x280000, 0, 0x100000, stream);

    prep_kernel<<<64, 64, 0, stream>>>(log_dt, C_re, C_im, logAr, A_im, P);
    prep_w_kernel<<<64, 256, 0, stream>>>(outW,  WpO, 256, 1);
    prep_w_kernel<<<32, 256, 0, stream>>>(lin1W, WpL, 256, 0);
    prep_w_kernel<<<128, 256, 0, stream>>>(gluW, WpG, 512, 1);
    prep_w_kernel<<<32, 256, 0, stream>>>(ff2aW, WpA, 256, 0);
    prep_w_kernel<<<32, 256, 0, stream>>>(ff2bW, WpB, 256, 0);

    // x -> channels-last bf16 + LN1 partial stats, then finalize
    transpose_kernel<float, true><<<dim3(128, 4, BN), 256, 0, stream>>>(x, x_cl, s1, ss1);
    ln_fin_kernel<<<256, 256, 0, stream>>>(s1, ss1, mu1, rs1);

    __bf16* gu_raw = (__bf16*)slC;
    __bf16* gu_cl  = (__bf16*)slB;
    scan_kernel<<<2048, 512, 0, stream>>>(x, mu1, rs1, ln1g, ln1b, Dp, P, gu_raw);
    transpose_kernel<__bf16, false><<<dim3(128, 4, BN), 256, 0, stream>>>(gu_raw, gu_cl,
                                                                          nullptr, nullptr);

    __bf16* y2g = (__bf16*)slC;   // overwrites gu_raw
    __bf16* y3  = (__bf16*)slB;   // overwrites gu_cl
    __bf16* A_bf = (__bf16*)slC;  // overwrites y2g after GEMM2
    __bf16* t1  = (__bf16*)slB;   // overwrites y3 after GEMM3

    // GEMM1: y2g = gelu(GLU(outW · gu + outB))     grid 512*4
    gemm_cl_kernel<256, 4, true, false, false, true, 0><<<2048, 256, 0, stream>>>(
        gu_cl, nullptr, nullptr, WpO, outB, nullptr, nullptr, nullptr, nullptr,
        nullptr, nullptr, nullptr, nullptr, y2g);
    // GEMM2: y3 = lin1 · y2g + lin1b               grid 512*2
    gemm_cl_kernel<256, 2, false, false, false, false, 0><<<1024, 256, 0, stream>>>(
        y2g, nullptr, nullptr, WpL, lin1b, nullptr, nullptr, nullptr, nullptr,
        nullptr, nullptr, nullptr, nullptr, y3);
    // GEMM3: A_bf = x + GLU(gluW · [x_cl; y3] + glub), + LN2 partial stats
    gemm_cl_kernel<512, 4, true, true, false, false, 1><<<2048, 256, 0, stream>>>(
        x_cl, y3, nullptr, WpG, glub, nullptr, nullptr, nullptr, nullptr,
        x_cl, s2, ss2, nullptr, A_bf);
    ln_fin_kernel<<<256, 256, 0, stream>>>(s2, ss2, mu2, rs2);
    // GEMM4: t1 = gelu(ff2a · LN2(A) + ff2ab)
    gemm_cl_kernel<256, 2, false, false, true, true, 0><<<1024, 256, 0, stream>>>(
        nullptr, nullptr, A_bf, WpA, ff2ab, mu2, rs2, ln2g, ln2b,
        nullptr, nullptr, nullptr, nullptr, t1);
    // GEMM5: out = A + ff2b · t1 + ff2bb   (fp32 [B][H][T])
    gemm_cl_kernel<256, 2, false, false, false, false, 2><<<1024, 256, 0, stream>>>(
        t1, nullptr, nullptr, WpB, ff2bb, nullptr, nullptr, nullptr, nullptr,
        A_bf, nullptr, nullptr, out, nullptr);
}

// Round 10
// 430.859 us; speedup vs baseline: 2.6012x; 2.6012x over previous
//
#include <hip/hip_runtime.h>
#include <math.h>

// S4D block, MI355X round 10: 512-thread scan with relaxed launch_bounds (no spill).
// B=8, H=256, T=8192, N=16 complex states.

#define TN 8192
#define HN 256
#define BN 8
#define NS 16

typedef __bf16 bf16x8 __attribute__((ext_vector_type(8)));
typedef __bf16 bf16x4 __attribute__((ext_vector_type(4)));
typedef __bf16 bf16x2 __attribute__((ext_vector_type(2)));
typedef float  f32x4  __attribute__((ext_vector_type(4)));

__device__ __forceinline__ float gelu_f(float v) {
    return 0.5f * v * (1.f + erff(v * 0.70710678118654752440f));
}
__device__ __forceinline__ float sigm_f(float v) {
    return 1.f / (1.f + expf(-v));
}

// ---------------- SSM constant prep: store dt*A + 2*Cmod ----------------
__global__ void prep_kernel(const float* __restrict__ log_dt,
                            const float* __restrict__ C_re,
                            const float* __restrict__ C_im,
                            const float* __restrict__ log_A_real,
                            const float* __restrict__ A_imag,
                            float* __restrict__ P)
{
    int i = blockIdx.x * 64 + threadIdx.x;   // 0..4095
    int h = i >> 4;
    float dt = expf(log_dt[h]);
    float Ar = -expf(log_A_real[i]);
    float Ai = A_imag[i];
    float dar = Ar * dt, dai = Ai * dt;
    float er = expf(dar);
    float ar = er * cosf(dai);
    float ai = er * sinf(dai);
    float Er = ar - 1.f, Ei = ai;
    float inv = 1.f / (Ar * Ar + Ai * Ai);
    float Fr = (Er * Ar + Ei * Ai) * inv;
    float Fi = (Ei * Ar - Er * Ai) * inv;
    float cr = C_re[i] * Fr - C_im[i] * Fi;
    float ci = C_re[i] * Fi + C_im[i] * Fr;
    P[i]           = dar;
    P[4096 + i]    = dai;
    P[2*4096 + i]  = 2.f * cr;
    P[3*4096 + i]  = 2.f * ci;
}

// ---------------- weight prep: fp32 -> bf16, tiled+swizzled LDS image ----------------
__global__ void prep_w_kernel(const float* __restrict__ W, __bf16* __restrict__ Wp,
                              int K, int glu)
{
    int id = blockIdx.x * 256 + threadIdx.x;
    int nK = K >> 6;
    int c = id >> 10, r = (id >> 3) & 127, s = id & 7;
    int mt = c / nK, kt = c - mt * nK;
    int R = mt * 128 + r;
    int row = glu ? ((R & 1) ? (R >> 1) + 256 : (R >> 1)) : R;
    int k = kt * 64 + ((s ^ (r & 7)) << 3);
    const float* src = W + (size_t)row * K + k;
    __bf16 o[8];
    #pragma unroll
    for (int j = 0; j < 8; ++j) o[j] = (__bf16)src[j];
    *(uint4*)(Wp + (size_t)id * 8) = *(uint4*)o;
}

// ---------------- LN stats finalize ----------------
__global__ __launch_bounds__(256) void ln_fin_kernel(const float* __restrict__ s,
                                                     const float* __restrict__ ss,
                                                     float* __restrict__ mu,
                                                     float* __restrict__ rs)
{
    int i = blockIdx.x * 256 + threadIdx.x;   // 0..65535
    float m = s[i] * (1.f / 256.f);
    mu[i] = m;
    rs[i] = rsqrtf(ss[i] * (1.f / 256.f) - m * m + 1e-5f);
}

// ---------------- transpose [B][H][T] (f32 or bf16) -> [B][T][H] bf16, optional LN stats ----------------
template<typename TI, bool STATS>
__global__ __launch_bounds__(256) void transpose_kernel(const TI* __restrict__ in,
                                                        __bf16* __restrict__ out,
                                                        float* __restrict__ sAcc,
                                                        float* __restrict__ ssAcc)
{
    __shared__ float tile[64][65];
    int b = blockIdx.z, h0 = blockIdx.y * 64, t0 = blockIdx.x * 64;
    int tid = threadIdx.x;
    int hl = tid >> 2, pr = tid & 3;
    const TI* src = in + ((size_t)(b * HN + h0 + hl)) * TN + t0 + pr * 16;
    if constexpr (sizeof(TI) == 4) {
        #pragma unroll
        for (int j = 0; j < 4; ++j) {
            float4 v = *(const float4*)((const float*)src + j * 4);
            *(float4*)&tile[hl][pr * 16 + j * 4] = v;
        }
    } else {
        #pragma unroll
        for (int p = 0; p < 2; ++p) {
            bf16x8 v = *(const bf16x8*)((const __bf16*)src + p * 8);
            #pragma unroll
            for (int j = 0; j < 8; ++j) tile[hl][pr * 16 + p * 8 + j] = (float)v[j];
        }
    }
    __syncthreads();
    int tl = tid >> 2;
    __bf16 o[16];
    #pragma unroll
    for (int j = 0; j < 16; ++j) o[j] = (__bf16)tile[pr * 16 + j][tl];
    __bf16* dst = out + ((size_t)(b * TN + t0 + tl)) * HN + h0 + pr * 16;
    *(uint4*)dst = *(uint4*)&o[0];
    *(uint4*)(dst + 8) = *(uint4*)&o[8];
    if constexpr (STATS) {
        if (tid < 64) {
            float s = 0.f, ss = 0.f;
            #pragma unroll 8
            for (int hh = 0; hh < 64; ++hh) {
                float v = tile[hh][tid];
                s += v; ss += v * v;
            }
            atomicAdd(&sAcc[b * TN + t0 + tid], s);
            atomicAdd(&ssAcc[b * TN + t0 + tid], ss);
        }
    }
}

// ---------------- S4D scan: 512 threads, chunk=16 elems, 16 states/thread ----------------
// KS over 64 lanes (decay a^(16*2^k)) + 8-wave combine (a^1024).
// launch_bounds(512,4): allocator free to use <=128 VGPR; natural ~64 -> 32 waves/CU.
__global__ __launch_bounds__(512, 4) void scan_kernel(const float* __restrict__ X,
                                                      const float* __restrict__ mu,
                                                      const float* __restrict__ rs,
                                                      const float* __restrict__ g1,
                                                      const float* __restrict__ b1,
                                                      const float* __restrict__ Dp,
                                                      const float* __restrict__ P,
                                                      __bf16* __restrict__ GU)
{
    __shared__ float ylds[512 * 17];      // 34816B
    __shared__ float astab[16][2];
    __shared__ float c2tab[16][2];
    __shared__ float ksd[7][16][2];       // a^(16*2^k), k=0..6 (k=6 -> a^1024)
    __shared__ float wtot[8][16][2];
    int row = blockIdx.x;
    int b = row >> 8, h = row & 255;
    int tid = threadIdx.x;
    int w = tid >> 6, l = tid & 63;

    float gh = g1[h], bh = b1[h], dh = Dp[h];
    const float* xrow = X + (size_t)(b * HN + h) * TN;
    const float* mup = mu + b * TN;
    const float* rsp = rs + b * TN;

    // ---- tables, spread over threads ----
    if (tid < 112) {
        int k = tid >> 4, n = tid & 15;
        float dar = P[h * NS + n], dai = P[4096 + h * NS + n];
        float m = (float)(16 << k);
        float er = expf(m * dar), ph = m * dai;
        ksd[k][n][0] = er * cosf(ph);
        ksd[k][n][1] = er * sinf(ph);
    } else if (tid < 128) {
        int n = tid & 15;
        float dar = P[h * NS + n], dai = P[4096 + h * NS + n];
        float e1 = expf(dar);
        astab[n][0] = e1 * cosf(dai);
        astab[n][1] = e1 * sinf(dai);
        c2tab[n][0] = P[2*4096 + h * NS + n];
        c2tab[n][1] = P[3*4096 + h * NS + n];
    }

    // ---- stage row + inline LN1 ----
    #pragma unroll 2
    for (int s = 0; s < 4; ++s) {
        int t = (s * 512 + tid) * 4;
        float4 xv = *(const float4*)(xrow + t);
        float4 m4 = *(const float4*)(mup + t);
        float4 r4 = *(const float4*)(rsp + t);
        float* dst = &ylds[(t >> 4) * 17 + (t & 15)];
        dst[0] = fmaf((xv.x - m4.x) * r4.x, gh, bh);
        dst[1] = fmaf((xv.y - m4.y) * r4.y, gh, bh);
        dst[2] = fmaf((xv.z - m4.z) * r4.z, gh, bh);
        dst[3] = fmaf((xv.w - m4.w) * r4.w, gh, bh);
    }
    __syncthreads();

    float ar_[16], ai_[16];
    #pragma unroll
    for (int n = 0; n < 16; ++n) { ar_[n] = astab[n][0]; ai_[n] = astab[n][1]; }

    // ---- pass A: chunk summary (16 elems) ----
    float sr[16], si[16];
    #pragma unroll
    for (int n = 0; n < 16; ++n) { sr[n] = 0.f; si[n] = 0.f; }
    const float* yc = &ylds[tid * 17];
    #pragma unroll 1
    for (int g = 0; g < 2; ++g) {
        float yv[8];
        #pragma unroll
        for (int e = 0; e < 8; ++e) yv[e] = yc[g * 8 + e];
        #pragma unroll
        for (int e = 0; e < 8; ++e) {
            float y = yv[e];
            #pragma unroll
            for (int n = 0; n < 16; ++n) {
                float nr = fmaf(ar_[n], sr[n], fmaf(-ai_[n], si[n], y));
                si[n] = fmaf(ar_[n], si[n], ai_[n] * sr[n]);
                sr[n] = nr;
            }
        }
    }

    // ---- Kogge-Stone over 64 chunks in wave ----
    #pragma unroll
    for (int k = 0; k < 6; ++k) {
        int d = 1 << k;
        #pragma unroll
        for (int n = 0; n < 16; ++n) {
            float qpr = __shfl_up(sr[n], (unsigned)d, 64);
            float qpi = __shfl_up(si[n], (unsigned)d, 64);
            if (l >= d) {
                float pdr = ksd[k][n][0], pdi = ksd[k][n][1];
                sr[n] = fmaf(pdr, qpr, fmaf(-pdi, qpi, sr[n]));
                si[n] = fmaf(pdr, qpi, fmaf(pdi, qpr, si[n]));
            }
        }
    }
    if (l == 63) {
        #pragma unroll
        for (int n = 0; n < 16; ++n) { wtot[w][n][0] = sr[n]; wtot[w][n][1] = si[n]; }
    }
    __syncthreads();

    // ---- s_init per chunk ----
    #pragma unroll
    for (int n = 0; n < 16; ++n) {
        float Lr = __shfl_up(sr[n], 1u, 64);
        float Li = __shfl_up(si[n], 1u, 64);
        if (l == 0) { Lr = 0.f; Li = 0.f; }
        float Sr = 0.f, Si = 0.f;
        float d6r = ksd[6][n][0], d6i = ksd[6][n][1];
        for (int v = 0; v < w; ++v) {
            float tr = fmaf(d6r, Sr, fmaf(-d6i, Si, wtot[v][n][0]));
            float ti = fmaf(d6r, Si, fmaf(d6i, Sr, wtot[v][n][1]));
            Sr = tr; Si = ti;
        }
        float qr = 1.f, qi = 0.f;
        #pragma unroll
        for (int k = 0; k < 6; ++k) {
            if ((l >> k) & 1) {
                float kr = ksd[k][n][0], ki = ksd[k][n][1];
                float t2 = qr * kr - qi * ki;
                qi = fmaf(qr, ki, qi * kr);
                qr = t2;
            }
        }
        sr[n] = fmaf(qr, Sr, fmaf(-qi, Si, Lr));
        si[n] = fmaf(qr, Si, fmaf(qi, Sr, Li));
    }

    float c2r_[16], c2i_[16];
    #pragma unroll
    for (int n = 0; n < 16; ++n) { c2r_[n] = c2tab[n][0]; c2i_[n] = c2tab[n][1]; }

    // ---- pass B: seeded rescan, emit gelu(u) in place ----
    float* yw = &ylds[tid * 17];
    #pragma unroll 1
    for (int g = 0; g < 2; ++g) {
        float yv[8];
        #pragma unroll
        for (int e = 0; e < 8; ++e) yv[e] = yw[g * 8 + e];
        #pragma unroll
        for (int e = 0; e < 8; ++e) {
            float y = yv[e];
            float u = dh * y;
            #pragma unroll
            for (int n = 0; n < 16; ++n) {
                float nr = fmaf(ar_[n], sr[n], fmaf(-ai_[n], si[n], y));
                si[n] = fmaf(ar_[n], si[n], ai_[n] * sr[n]);
                sr[n] = nr;
                u = fmaf(c2r_[n], nr, fmaf(-c2i_[n], si[n], u));
            }
            yv[e] = gelu_f(u);
        }
        #pragma unroll
        for (int e = 0; e < 8; ++e) yw[g * 8 + e] = yv[e];
    }
    __syncthreads();

    // ---- coalesced bf16 write ----
    __bf16* gout = GU + (size_t)(b * HN + h) * TN;
    #pragma unroll 2
    for (int s = 0; s < 4; ++s) {
        int t = (s * 512 + tid) * 4;
        const float* src = &ylds[(t >> 4) * 17 + (t & 15)];
        bf16x4 ov;
        ov[0] = (__bf16)src[0]; ov[1] = (__bf16)src[1];
        ov[2] = (__bf16)src[2]; ov[3] = (__bf16)src[3];
        *(bf16x4*)(gout + t) = ov;
    }
}

// ---------------- MFMA conv1x1 GEMM, channels-last, 1D XCD-swizzled grid ----------------
// OMODE 0: bf16 out [B][T][H]
// OMODE 1: bf16 A [B][T][H] = GLU + bf16 resB, + LN2 partial stats (atomics)
// OMODE 2: fp32 out [B][H][T] += bf16 resB (cl), LDS-transposed store
template<int K, int NTY, bool GLU, bool CONCAT, bool LNIN, bool GELUOUT, int OMODE>
__global__ __launch_bounds__(256) void gemm_cl_kernel(
    const __bf16* __restrict__ B0, const __bf16* __restrict__ B1,
    const __bf16* __restrict__ BA,
    const __bf16* __restrict__ Wp, const float* __restrict__ bias,
    const float* __restrict__ mu, const float* __restrict__ rsd,
    const float* __restrict__ lng, const float* __restrict__ lnb,
    const __bf16* __restrict__ resB,
    float* __restrict__ sAcc, float* __restrict__ ssAcc,
    float* __restrict__ outF, __bf16* __restrict__ outB)
{
    constexpr int nK = K / 64;
    constexpr int LDSSZ = (OMODE != 0) ? 34816 : 32768;
    __shared__ __align__(16) char lds[LDSSZ];
    char* sA = lds;
    char* sB = lds + 16384;
    int tid = threadIdx.x;
    int w = tid >> 6, wr = w >> 1, wc = w & 1;

    int f = blockIdx.x;
    int r8 = f & 7, m = f >> 3;
    int by = m % NTY;
    int c = (m / NTY) * 8 + r8;
    int b = c >> 6;
    int t0 = (c & 63) * 128;

    int lane = tid & 63;
    int lr = tid & 15, lg = (tid >> 4) & 3;
    int rl = lane >> 3, sl = lane & 7;

    f32x4 acc[4][4];
    #pragma unroll
    for (int i = 0; i < 4; ++i)
        #pragma unroll
        for (int j = 0; j < 4; ++j) acc[i][j] = (f32x4){0.f, 0.f, 0.f, 0.f};

    for (int kt = 0; kt < nK; ++kt) {
        {
            const char* asrc = (const char*)Wp + (((size_t)by * nK + kt) << 14)
                               + w * 4096 + lane * 16;
            char* adst = sA + w * 4096;
            #pragma unroll
            for (int i = 0; i < 4; ++i)
                __builtin_amdgcn_global_load_lds(
                    (const __attribute__((address_space(1))) void*)(asrc + i * 1024),
                    (__attribute__((address_space(3))) void*)(adst + i * 1024), 16, 0, 0);
        }
        if constexpr (!LNIN) {
            int kg = kt * 64;
            const __bf16* base = (CONCAT && kg >= 256) ? B1 : B0;
            int kloc = (CONCAT && kg >= 256) ? kg - 256 : kg;
            #pragma unroll
            for (int i = 0; i < 4; ++i) {
                int rb = w * 32 + i * 8 + rl;
                const char* gs = (const char*)(base + (((size_t)(b * TN + t0 + rb)) << 8) + kloc)
                                 + ((sl ^ rl) << 4);
                __builtin_amdgcn_global_load_lds(
                    (const __attribute__((address_space(1))) void*)gs,
                    (__attribute__((address_space(3))) void*)(sB + w * 4096 + i * 1024), 16, 0, 0);
            }
        } else {
            #pragma unroll
            for (int i = 0; i < 8; ++i) {
                int q = i * 256 + tid;
                int rq = q >> 4, qs = q & 15;
                int t = t0 + rq;
                bf16x4 av = *(const bf16x4*)(BA + (((size_t)(b * TN + t)) << 8) + kt * 64 + qs * 4);
                float m_ = mu[b * TN + t], rr = rsd[b * TN + t];
                float4 g4 = *(const float4*)(lng + kt * 64 + qs * 4);
                float4 b4 = *(const float4*)(lnb + kt * 64 + qs * 4);
                __bf16 o[4];
                o[0] = (__bf16)fmaf(((float)av[0] - m_) * rr, g4.x, b4.x);
                o[1] = (__bf16)fmaf(((float)av[1] - m_) * rr, g4.y, b4.y);
                o[2] = (__bf16)fmaf(((float)av[2] - m_) * rr, g4.z, b4.z);
                o[3] = (__bf16)fmaf(((float)av[3] - m_) * rr, g4.w, b4.w);
                int off = rq * 128 + ((((qs >> 1) ^ (rq & 7))) << 4) + (qs & 1) * 8;
                *(uint2*)(sB + off) = *(uint2*)o;
            }
        }
        __syncthreads();

        const char* aB = sA + (wr * 64 + lr) * 128;
        const char* bB = sB + (wc * 64 + lr) * 128;
        int swz = (lr & 7) << 4;
        #pragma unroll
        for (int ks = 0; ks < 2; ++ks) {
            int ko = (ks * 64 + lg * 16) ^ swz;
            bf16x8 af[4], bfr[4];
            #pragma unroll
            for (int ff = 0; ff < 4; ++ff) af[ff]  = *(const bf16x8*)(aB + ff * 2048 + ko);
            #pragma unroll
            for (int ff = 0; ff < 4; ++ff) bfr[ff] = *(const bf16x8*)(bB + ff * 2048 + ko);
            #pragma unroll
            for (int fm = 0; fm < 4; ++fm)
                #pragma unroll
                for (int fn = 0; fn < 4; ++fn)
                    acc[fm][fn] = __builtin_amdgcn_mfma_f32_16x16x32_bf16(
                        af[fm], bfr[fn], acc[fm][fn], 0, 0, 0);
        }
        __syncthreads();
    }

    int tcb = t0 + wc * 64 + lr;
    int mrow0 = by * 128 + wr * 64 + lg * 4;

    if constexpr (OMODE == 1) {
        float* tile = (float*)lds;
        #pragma unroll
        for (int fm = 0; fm < 4; ++fm) {
            int R0 = mrow0 + fm * 16;
            int c_ = R0 >> 1;
            int cloc = c_ - by * 64;
            #pragma unroll
            for (int fn = 0; fn < 4; ++fn) {
                f32x4 v = acc[fm][fn];
                float a0 = v[0] + bias[c_],     g0 = v[1] + bias[c_ + 256];
                float a1 = v[2] + bias[c_ + 1], g1 = v[3] + bias[c_ + 257];
                float o0 = a0 * sigm_f(g0), o1 = a1 * sigm_f(g1);
                int tl = wc * 64 + lr + fn * 16;
                *(float2*)&tile[tl * 68 + cloc] = make_float2(o0, o1);
            }
        }
        __syncthreads();
        #pragma unroll
        for (int it = 0; it < 8; ++it) {
            int fid = it * 256 + tid;
            int tl = fid >> 4, fc = (fid & 15) << 2;
            size_t go = (((size_t)(b * TN + t0 + tl)) << 8) + by * 64 + fc;
            float4 v = *(const float4*)&tile[tl * 68 + fc];
            bf16x4 xr = *(const bf16x4*)(resB + go);
            v.x += (float)xr[0]; v.y += (float)xr[1];
            v.z += (float)xr[2]; v.w += (float)xr[3];
            *(float4*)&tile[tl * 68 + fc] = v;
            bf16x4 ov;
            ov[0] = (__bf16)v.x; ov[1] = (__bf16)v.y;
            ov[2] = (__bf16)v.z; ov[3] = (__bf16)v.w;
            *(bf16x4*)(outB + go) = ov;
        }
        __syncthreads();
        if (tid < 128) {
            const float* rowp = &tile[tid * 68];
            float s = 0.f, ss = 0.f;
            #pragma unroll 8
            for (int cc = 0; cc < 64; ++cc) {
                float v = rowp[cc];
                s += v; ss += v * v;
            }
            atomicAdd(&sAcc[b * TN + t0 + tid], s);
            atomicAdd(&ssAcc[b * TN + t0 + tid], ss);
        }
    } else if constexpr (OMODE == 2) {
        float* tile = (float*)lds;
        #pragma unroll
        for (int ht = 0; ht < 2; ++ht) {
            if (wc == ht) {
                #pragma unroll
                for (int fm = 0; fm < 4; ++fm) {
                    int R0 = mrow0 + fm * 16;
                    int mloc = R0 - by * 128;
                    #pragma unroll
                    for (int fn = 0; fn < 4; ++fn) {
                        int t = tcb + fn * 16;
                        f32x4 v = acc[fm][fn];
                        bf16x4 rv = *(const bf16x4*)(resB + (((size_t)(b * TN + t)) << 8) + R0);
                        int tloc = lr + fn * 16;
                        tile[(mloc + 0) * 68 + tloc] = v[0] + bias[R0 + 0] + (float)rv[0];
                        tile[(mloc + 1) * 68 + tloc] = v[1] + bias[R0 + 1] + (float)rv[1];
                        tile[(mloc + 2) * 68 + tloc] = v[2] + bias[R0 + 2] + (float)rv[2];
                        tile[(mloc + 3) * 68 + tloc] = v[3] + bias[R0 + 3] + (float)rv[3];
                    }
                }
            }
            __syncthreads();
            #pragma unroll
            for (int it = 0; it < 8; ++it) {
                int fid = it * 256 + tid;
                int mm = fid >> 4, fc = (fid & 15) << 2;
                float4 v = *(const float4*)&tile[mm * 68 + fc];
                *(float4*)(outF + ((size_t)(b * HN + by * 128 + mm)) * TN + t0 + ht * 64 + fc) = v;
            }
            __syncthreads();
        }
    } else {
        #pragma unroll
        for (int fm = 0; fm < 4; ++fm) {
            int R0 = mrow0 + fm * 16;
            #pragma unroll
            for (int fn = 0; fn < 4; ++fn) {
                int t = tcb + fn * 16;
                f32x4 v = acc[fm][fn];
                size_t rowoff = ((size_t)(b * TN + t)) << 8;
                if constexpr (GLU) {
                    int c_ = R0 >> 1;
                    float a0 = v[0] + bias[c_],     g0 = v[1] + bias[c_ + 256];
                    float a1 = v[2] + bias[c_ + 1], g1 = v[3] + bias[c_ + 257];
                    float o0 = a0 * sigm_f(g0), o1 = a1 * sigm_f(g1);
                    if constexpr (GELUOUT) { o0 = gelu_f(o0); o1 = gelu_f(o1); }
                    bf16x2 ov; ov[0] = (__bf16)o0; ov[1] = (__bf16)o1;
                    *(bf16x2*)(outB + rowoff + c_) = ov;
                } else {
                    float vv[4];
                    #pragma unroll
                    for (int j = 0; j < 4; ++j) vv[j] = v[j] + bias[R0 + j];
                    if constexpr (GELUOUT) {
                        #pragma unroll
                        for (int j = 0; j < 4; ++j) vv[j] = gelu_f(vv[j]);
                    }
                    bf16x4 ov;
                    #pragma unroll
                    for (int j = 0; j < 4; ++j) ov[j] = (__bf16)vv[j];
                    *(bf16x4*)(outB + rowoff + R0) = ov;
                }
            }
        }
    }
}

extern "C" void kernel_launch(void* const* d_in, const int* in_sizes, int n_in,
                              void* d_out, int out_size, void* d_ws, size_t ws_size,
                              hipStream_t stream)
{
    (void)in_sizes; (void)n_in; (void)out_size; (void)ws_size;
    const float* x      = (const float*)d_in[0];
    const float* log_dt = (const float*)d_in[1];
    const float* C_re   = (const float*)d_in[2];
    const float* C_im   = (const float*)d_in[3];
    const float* logAr  = (const float*)d_in[4];
    const float* A_im   = (const float*)d_in[5];
    const float* Dp     = (const float*)d_in[6];
    const float* outW   = (const float*)d_in[7];
    const float* outB   = (const float*)d_in[8];
    const float* ln1g   = (const float*)d_in[9];
    const float* ln1b   = (const float*)d_in[10];
    const float* lin1W  = (const float*)d_in[11];
    const float* lin1b  = (const float*)d_in[12];
    const float* gluW   = (const float*)d_in[13];
    const float* glub   = (const float*)d_in[14];
    const float* ln2g   = (const float*)d_in[15];
    const float* ln2b   = (const float*)d_in[16];
    const float* ff2aW  = (const float*)d_in[17];
    const float* ff2ab  = (const float*)d_in[18];
    const float* ff2bW  = (const float*)d_in[19];
    const float* ff2bb  = (const float*)d_in[20];
    float* out = (float*)d_out;

    char* ws = (char*)d_ws;
    const size_t MB = 1u << 20;
    float*  P    = (float*)(ws);
    float*  mu1  = (float*)(ws + 0x40000);
    float*  rs1  = (float*)(ws + 0x80000);
    float*  mu2  = (float*)(ws + 0xC0000);
    float*  rs2  = (float*)(ws + 0x100000);
    __bf16* WpO  = (__bf16*)(ws + 0x140000);
    __bf16* WpL  = (__bf16*)(ws + 0x180000);
    __bf16* WpG  = (__bf16*)(ws + 0x1A0000);
    __bf16* WpA  = (__bf16*)(ws + 0x220000);
    __bf16* WpB  = (__bf16*)(ws + 0x240000);
    float*  s1   = (float*)(ws + 0x280000);
    float*  ss1  = (float*)(ws + 0x2C0000);
    float*  s2   = (float*)(ws + 0x300000);
    float*  ss2  = (float*)(ws + 0x340000);
    __bf16* x_cl = (__bf16*)(ws + 4 * MB);     // 32MB [B][T][H] bf16
    char*   slB  = ws + 36 * MB;               // 32MB
    char*   slC  = ws + 68 * MB;               // 32MB

    // zero stats accumulators (s1,ss1,s2,ss2 contiguous 1MB)
    hipMemsetAsync(ws + 0x280000, 0, 0x100000, stream);

    prep_kernel<<<64, 64, 0, stream>>>(log_dt, C_re, C_im, logAr, A_im, P);
    prep_w_kernel<<<64, 256, 0, stream>>>(outW,  WpO, 256, 1);
    prep_w_kernel<<<32, 256, 0, stream>>>(lin1W, WpL, 256, 0);
    prep_w_kernel<<<128, 256, 0, stream>>>(gluW, WpG, 512, 1);
    prep_w_kernel<<<32, 256, 0, stream>>>(ff2aW, WpA, 256, 0);
    prep_w_kernel<<<32, 256, 0, stream>>>(ff2bW, WpB, 256, 0);

    // x -> channels-last bf16 + LN1 partial stats, then finalize
    transpose_kernel<float, true><<<dim3(128, 4, BN), 256, 0, stream>>>(x, x_cl, s1, ss1);
    ln_fin_kernel<<<256, 256, 0, stream>>>(s1, ss1, mu1, rs1);

    __bf16* gu_raw = (__bf16*)slC;
    __bf16* gu_cl  = (__bf16*)slB;
    scan_kernel<<<2048, 512, 0, stream>>>(x, mu1, rs1, ln1g, ln1b, Dp, P, gu_raw);
    transpose_kernel<__bf16, false><<<dim3(128, 4, BN), 256, 0, stream>>>(gu_raw, gu_cl,
                                                                          nullptr, nullptr);

    __bf16* y2g = (__bf16*)slC;   // overwrites gu_raw
    __bf16* y3  = (__bf16*)slB;   // overwrites gu_cl
    __bf16* A_bf = (__bf16*)slC;  // overwrites y2g after GEMM2
    __bf16* t1  = (__bf16*)slB;   // overwrites y3 after GEMM3

    // GEMM1: y2g = gelu(GLU(outW · gu + outB))     grid 512*4
    gemm_cl_kernel<256, 4, true, false, false, true, 0><<<2048, 256, 0, stream>>>(
        gu_cl, nullptr, nullptr, WpO, outB, nullptr, nullptr, nullptr, nullptr,
        nullptr, nullptr, nullptr, nullptr, y2g);
    // GEMM2: y3 = lin1 · y2g + lin1b               grid 512*2
    gemm_cl_kernel<256, 2, false, false, false, false, 0><<<1024, 256, 0, stream>>>(
        y2g, nullptr, nullptr, WpL, lin1b, nullptr, nullptr, nullptr, nullptr,
        nullptr, nullptr, nullptr, nullptr, y3);
    // GEMM3: A_bf = x + GLU(gluW · [x_cl; y3] + glub), + LN2 partial stats
    gemm_cl_kernel<512, 4, true, true, false, false, 1><<<2048, 256, 0, stream>>>(
        x_cl, y3, nullptr, WpG, glub, nullptr, nullptr, nullptr, nullptr,
        x_cl, s2, ss2, nullptr, A_bf);
    ln_fin_kernel<<<256, 256, 0, stream>>>(s2, ss2, mu2, rs2);
    // GEMM4: t1 = gelu(ff2a · LN2(A) + ff2ab)
    gemm_cl_kernel<256, 2, false, false, true, true, 0><<<1024, 256, 0, stream>>>(
        nullptr, nullptr, A_bf, WpA, ff2ab, mu2, rs2, ln2g, ln2b,
        nullptr, nullptr, nullptr, nullptr, t1);
    // GEMM5: out = A + ff2b · t1 + ff2bb   (fp32 [B][H][T])
    gemm_cl_kernel<256, 2, false, false, false, false, 2><<<1024, 256, 0, stream>>>(
        t1, nullptr, nullptr, WpB, ff2bb, nullptr, nullptr, nullptr, nullptr,
        A_bf, nullptr, nullptr, out, nullptr);
}

// Round 11
// 376.810 us; speedup vs baseline: 2.9743x; 1.1434x over previous
//
#include <hip/hip_runtime.h>
#include <math.h>

// S4D block, MI355X round 11: revert scan to round-8 optimum + setprio on scan passes.
// B=8, H=256, T=8192, N=16 complex states.

#define TN 8192
#define HN 256
#define BN 8
#define NS 16

typedef __bf16 bf16x8 __attribute__((ext_vector_type(8)));
typedef __bf16 bf16x4 __attribute__((ext_vector_type(4)));
typedef __bf16 bf16x2 __attribute__((ext_vector_type(2)));
typedef float  f32x4  __attribute__((ext_vector_type(4)));

__device__ __forceinline__ float gelu_f(float v) {
    return 0.5f * v * (1.f + erff(v * 0.70710678118654752440f));
}
__device__ __forceinline__ float sigm_f(float v) {
    return 1.f / (1.f + expf(-v));
}

// ---------------- SSM constant prep: store dt*A + 2*Cmod ----------------
__global__ void prep_kernel(const float* __restrict__ log_dt,
                            const float* __restrict__ C_re,
                            const float* __restrict__ C_im,
                            const float* __restrict__ log_A_real,
                            const float* __restrict__ A_imag,
                            float* __restrict__ P)
{
    int i = blockIdx.x * 64 + threadIdx.x;   // 0..4095
    int h = i >> 4;
    float dt = expf(log_dt[h]);
    float Ar = -expf(log_A_real[i]);
    float Ai = A_imag[i];
    float dar = Ar * dt, dai = Ai * dt;
    float er = expf(dar);
    float ar = er * cosf(dai);
    float ai = er * sinf(dai);
    float Er = ar - 1.f, Ei = ai;
    float inv = 1.f / (Ar * Ar + Ai * Ai);
    float Fr = (Er * Ar + Ei * Ai) * inv;
    float Fi = (Ei * Ar - Er * Ai) * inv;
    float cr = C_re[i] * Fr - C_im[i] * Fi;
    float ci = C_re[i] * Fi + C_im[i] * Fr;
    P[i]           = dar;
    P[4096 + i]    = dai;
    P[2*4096 + i]  = 2.f * cr;
    P[3*4096 + i]  = 2.f * ci;
}

// ---------------- weight prep: fp32 -> bf16, tiled+swizzled LDS image ----------------
__global__ void prep_w_kernel(const float* __restrict__ W, __bf16* __restrict__ Wp,
                              int K, int glu)
{
    int id = blockIdx.x * 256 + threadIdx.x;
    int nK = K >> 6;
    int c = id >> 10, r = (id >> 3) & 127, s = id & 7;
    int mt = c / nK, kt = c - mt * nK;
    int R = mt * 128 + r;
    int row = glu ? ((R & 1) ? (R >> 1) + 256 : (R >> 1)) : R;
    int k = kt * 64 + ((s ^ (r & 7)) << 3);
    const float* src = W + (size_t)row * K + k;
    __bf16 o[8];
    #pragma unroll
    for (int j = 0; j < 8; ++j) o[j] = (__bf16)src[j];
    *(uint4*)(Wp + (size_t)id * 8) = *(uint4*)o;
}

// ---------------- LN stats finalize ----------------
__global__ __launch_bounds__(256) void ln_fin_kernel(const float* __restrict__ s,
                                                     const float* __restrict__ ss,
                                                     float* __restrict__ mu,
                                                     float* __restrict__ rs)
{
    int i = blockIdx.x * 256 + threadIdx.x;   // 0..65535
    float m = s[i] * (1.f / 256.f);
    mu[i] = m;
    rs[i] = rsqrtf(ss[i] * (1.f / 256.f) - m * m + 1e-5f);
}

// ---------------- transpose [B][H][T] (f32 or bf16) -> [B][T][H] bf16, optional LN stats ----------------
template<typename TI, bool STATS>
__global__ __launch_bounds__(256) void transpose_kernel(const TI* __restrict__ in,
                                                        __bf16* __restrict__ out,
                                                        float* __restrict__ sAcc,
                                                        float* __restrict__ ssAcc)
{
    __shared__ float tile[64][65];
    int b = blockIdx.z, h0 = blockIdx.y * 64, t0 = blockIdx.x * 64;
    int tid = threadIdx.x;
    int hl = tid >> 2, pr = tid & 3;
    const TI* src = in + ((size_t)(b * HN + h0 + hl)) * TN + t0 + pr * 16;
    if constexpr (sizeof(TI) == 4) {
        #pragma unroll
        for (int j = 0; j < 4; ++j) {
            float4 v = *(const float4*)((const float*)src + j * 4);
            *(float4*)&tile[hl][pr * 16 + j * 4] = v;
        }
    } else {
        #pragma unroll
        for (int p = 0; p < 2; ++p) {
            bf16x8 v = *(const bf16x8*)((const __bf16*)src + p * 8);
            #pragma unroll
            for (int j = 0; j < 8; ++j) tile[hl][pr * 16 + p * 8 + j] = (float)v[j];
        }
    }
    __syncthreads();
    int tl = tid >> 2;
    __bf16 o[16];
    #pragma unroll
    for (int j = 0; j < 16; ++j) o[j] = (__bf16)tile[pr * 16 + j][tl];
    __bf16* dst = out + ((size_t)(b * TN + t0 + tl)) * HN + h0 + pr * 16;
    *(uint4*)dst = *(uint4*)&o[0];
    *(uint4*)(dst + 8) = *(uint4*)&o[8];
    if constexpr (STATS) {
        if (tid < 64) {
            float s = 0.f, ss = 0.f;
            #pragma unroll 8
            for (int hh = 0; hh < 64; ++hh) {
                float v = tile[hh][tid];
                s += v; ss += v * v;
            }
            atomicAdd(&sAcc[b * TN + t0 + tid], s);
            atomicAdd(&ssAcc[b * TN + t0 + tid], ss);
        }
    }
}

// ---------------- S4D scan (round-8 optimum): 32-elem chunks, 16 states/thread ----------------
__global__ __launch_bounds__(256, 4) void scan_kernel(const float* __restrict__ X,
                                                      const float* __restrict__ mu,
                                                      const float* __restrict__ rs,
                                                      const float* __restrict__ g1,
                                                      const float* __restrict__ b1,
                                                      const float* __restrict__ Dp,
                                                      const float* __restrict__ P,
                                                      __bf16* __restrict__ GU)
{
    __shared__ float ylds[256 * 33];      // 33792B
    __shared__ float astab[16][2];
    __shared__ float c2tab[16][2];
    __shared__ float ksd[7][16][2];       // a^(32*2^k)
    __shared__ float wtot[4][16][2];
    int row = blockIdx.x;
    int b = row >> 8, h = row & 255;
    int tid = threadIdx.x;
    int w = tid >> 6, l = tid & 63;

    float gh = g1[h], bh = b1[h], dh = Dp[h];
    const float* xrow = X + (size_t)(b * HN + h) * TN;
    const float* mup = mu + b * TN;
    const float* rsp = rs + b * TN;

    // ---- tables, spread over 128 threads ----
    if (tid < 112) {
        int k = tid >> 4, n = tid & 15;
        float dar = P[h * NS + n], dai = P[4096 + h * NS + n];
        float m = (float)(32 << k);
        float er = expf(m * dar), ph = m * dai;
        ksd[k][n][0] = er * cosf(ph);
        ksd[k][n][1] = er * sinf(ph);
    } else if (tid < 128) {
        int n = tid & 15;
        float dar = P[h * NS + n], dai = P[4096 + h * NS + n];
        float e1 = expf(dar);
        astab[n][0] = e1 * cosf(dai);
        astab[n][1] = e1 * sinf(dai);
        c2tab[n][0] = P[2*4096 + h * NS + n];
        c2tab[n][1] = P[3*4096 + h * NS + n];
    }

    // ---- stage row + inline LN1 ----
    #pragma unroll 2
    for (int s = 0; s < 8; ++s) {
        int t = (s * 256 + tid) * 4;
        float4 xv = *(const float4*)(xrow + t);
        float4 m4 = *(const float4*)(mup + t);
        float4 r4 = *(const float4*)(rsp + t);
        float* dst = &ylds[(t >> 5) * 33 + (t & 31)];
        dst[0] = fmaf((xv.x - m4.x) * r4.x, gh, bh);
        dst[1] = fmaf((xv.y - m4.y) * r4.y, gh, bh);
        dst[2] = fmaf((xv.z - m4.z) * r4.z, gh, bh);
        dst[3] = fmaf((xv.w - m4.w) * r4.w, gh, bh);
    }
    __syncthreads();

    float ar_[16], ai_[16];
    #pragma unroll
    for (int n = 0; n < 16; ++n) { ar_[n] = astab[n][0]; ai_[n] = astab[n][1]; }

    // ---- pass A: chunk summary ----
    float sr[16], si[16];
    #pragma unroll
    for (int n = 0; n < 16; ++n) { sr[n] = 0.f; si[n] = 0.f; }
    const float* yc = &ylds[tid * 33];
    __builtin_amdgcn_s_setprio(1);
    #pragma unroll 1
    for (int g = 0; g < 4; ++g) {
        float yv[8];
        #pragma unroll
        for (int e = 0; e < 8; ++e) yv[e] = yc[g * 8 + e];
        #pragma unroll
        for (int e = 0; e < 8; ++e) {
            float y = yv[e];
            #pragma unroll
            for (int n = 0; n < 16; ++n) {
                float nr = fmaf(ar_[n], sr[n], fmaf(-ai_[n], si[n], y));
                si[n] = fmaf(ar_[n], si[n], ai_[n] * sr[n]);
                sr[n] = nr;
            }
        }
    }
    __builtin_amdgcn_s_setprio(0);

    // ---- Kogge-Stone over 64 chunks in wave ----
    #pragma unroll
    for (int k = 0; k < 6; ++k) {
        int d = 1 << k;
        #pragma unroll
        for (int n = 0; n < 16; ++n) {
            float qpr = __shfl_up(sr[n], (unsigned)d, 64);
            float qpi = __shfl_up(si[n], (unsigned)d, 64);
            if (l >= d) {
                float pdr = ksd[k][n][0], pdi = ksd[k][n][1];
                sr[n] = fmaf(pdr, qpr, fmaf(-pdi, qpi, sr[n]));
                si[n] = fmaf(pdr, qpi, fmaf(pdi, qpr, si[n]));
            }
        }
    }
    if (l == 63) {
        #pragma unroll
        for (int n = 0; n < 16; ++n) { wtot[w][n][0] = sr[n]; wtot[w][n][1] = si[n]; }
    }
    __syncthreads();

    // ---- s_init per chunk ----
    #pragma unroll
    for (int n = 0; n < 16; ++n) {
        float Lr = __shfl_up(sr[n], 1u, 64);
        float Li = __shfl_up(si[n], 1u, 64);
        if (l == 0) { Lr = 0.f; Li = 0.f; }
        float Sr = 0.f, Si = 0.f;
        float d6r = ksd[6][n][0], d6i = ksd[6][n][1];
        for (int v = 0; v < w; ++v) {
            float tr = fmaf(d6r, Sr, fmaf(-d6i, Si, wtot[v][n][0]));
            float ti = fmaf(d6r, Si, fmaf(d6i, Sr, wtot[v][n][1]));
            Sr = tr; Si = ti;
        }
        float qr = 1.f, qi = 0.f;
        #pragma unroll
        for (int k = 0; k < 6; ++k) {
            if ((l >> k) & 1) {
                float kr = ksd[k][n][0], ki = ksd[k][n][1];
                float t2 = qr * kr - qi * ki;
                qi = fmaf(qr, ki, qi * kr);
                qr = t2;
            }
        }
        sr[n] = fmaf(qr, Sr, fmaf(-qi, Si, Lr));
        si[n] = fmaf(qr, Si, fmaf(qi, Sr, Li));
    }

    float c2r_[16], c2i_[16];
    #pragma unroll
    for (int n = 0; n < 16; ++n) { c2r_[n] = c2tab[n][0]; c2i_[n] = c2tab[n][1]; }

    // ---- pass B: seeded rescan, emit gelu(u) in place ----
    float* yw = &ylds[tid * 33];
    __builtin_amdgcn_s_setprio(1);
    #pragma unroll 1
    for (int g = 0; g < 4; ++g) {
        float yv[8];
        #pragma unroll
        for (int e = 0; e < 8; ++e) yv[e] = yw[g * 8 + e];
        #pragma unroll
        for (int e = 0; e < 8; ++e) {
            float y = yv[e];
            float u = dh * y;
            #pragma unroll
            for (int n = 0; n < 16; ++n) {
                float nr = fmaf(ar_[n], sr[n], fmaf(-ai_[n], si[n], y));
                si[n] = fmaf(ar_[n], si[n], ai_[n] * sr[n]);
                sr[n] = nr;
                u = fmaf(c2r_[n], nr, fmaf(-c2i_[n], si[n], u));
            }
            yw[g * 8 + e] = gelu_f(u);
        }
    }
    __builtin_amdgcn_s_setprio(0);
    __syncthreads();

    // ---- coalesced bf16 write ----
    __bf16* gout = GU + (size_t)(b * HN + h) * TN;
    #pragma unroll 2
    for (int s = 0; s < 8; ++s) {
        int t = (s * 256 + tid) * 4;
        const float* src = &ylds[(t >> 5) * 33 + (t & 31)];
        bf16x4 ov;
        ov[0] = (__bf16)src[0]; ov[1] = (__bf16)src[1];
        ov[2] = (__bf16)src[2]; ov[3] = (__bf16)src[3];
        *(bf16x4*)(gout + t) = ov;
    }
}

// ---------------- MFMA conv1x1 GEMM, channels-last, 1D XCD-swizzled grid ----------------
// OMODE 0: bf16 out [B][T][H]
// OMODE 1: bf16 A [B][T][H] = GLU + bf16 resB, + LN2 partial stats (atomics)
// OMODE 2: fp32 out [B][H][T] += bf16 resB (cl), LDS-transposed store
template<int K, int NTY, bool GLU, bool CONCAT, bool LNIN, bool GELUOUT, int OMODE>
__global__ __launch_bounds__(256) void gemm_cl_kernel(
    const __bf16* __restrict__ B0, const __bf16* __restrict__ B1,
    const __bf16* __restrict__ BA,
    const __bf16* __restrict__ Wp, const float* __restrict__ bias,
    const float* __restrict__ mu, const float* __restrict__ rsd,
    const float* __restrict__ lng, const float* __restrict__ lnb,
    const __bf16* __restrict__ resB,
    float* __restrict__ sAcc, float* __restrict__ ssAcc,
    float* __restrict__ outF, __bf16* __restrict__ outB)
{
    constexpr int nK = K / 64;
    constexpr int LDSSZ = (OMODE != 0) ? 34816 : 32768;
    __shared__ __align__(16) char lds[LDSSZ];
    char* sA = lds;
    char* sB = lds + 16384;
    int tid = threadIdx.x;
    int w = tid >> 6, wr = w >> 1, wc = w & 1;

    int f = blockIdx.x;
    int r8 = f & 7, m = f >> 3;
    int by = m % NTY;
    int c = (m / NTY) * 8 + r8;
    int b = c >> 6;
    int t0 = (c & 63) * 128;

    int lane = tid & 63;
    int lr = tid & 15, lg = (tid >> 4) & 3;
    int rl = lane >> 3, sl = lane & 7;

    f32x4 acc[4][4];
    #pragma unroll
    for (int i = 0; i < 4; ++i)
        #pragma unroll
        for (int j = 0; j < 4; ++j) acc[i][j] = (f32x4){0.f, 0.f, 0.f, 0.f};

    for (int kt = 0; kt < nK; ++kt) {
        {
            const char* asrc = (const char*)Wp + (((size_t)by * nK + kt) << 14)
                               + w * 4096 + lane * 16;
            char* adst = sA + w * 4096;
            #pragma unroll
            for (int i = 0; i < 4; ++i)
                __builtin_amdgcn_global_load_lds(
                    (const __attribute__((address_space(1))) void*)(asrc + i * 1024),
                    (__attribute__((address_space(3))) void*)(adst + i * 1024), 16, 0, 0);
        }
        if constexpr (!LNIN) {
            int kg = kt * 64;
            const __bf16* base = (CONCAT && kg >= 256) ? B1 : B0;
            int kloc = (CONCAT && kg >= 256) ? kg - 256 : kg;
            #pragma unroll
            for (int i = 0; i < 4; ++i) {
                int rb = w * 32 + i * 8 + rl;
                const char* gs = (const char*)(base + (((size_t)(b * TN + t0 + rb)) << 8) + kloc)
                                 + ((sl ^ rl) << 4);
                __builtin_amdgcn_global_load_lds(
                    (const __attribute__((address_space(1))) void*)gs,
                    (__attribute__((address_space(3))) void*)(sB + w * 4096 + i * 1024), 16, 0, 0);
            }
        } else {
            #pragma unroll
            for (int i = 0; i < 8; ++i) {
                int q = i * 256 + tid;
                int rq = q >> 4, qs = q & 15;
                int t = t0 + rq;
                bf16x4 av = *(const bf16x4*)(BA + (((size_t)(b * TN + t)) << 8) + kt * 64 + qs * 4);
                float m_ = mu[b * TN + t], rr = rsd[b * TN + t];
                float4 g4 = *(const float4*)(lng + kt * 64 + qs * 4);
                float4 b4 = *(const float4*)(lnb + kt * 64 + qs * 4);
                __bf16 o[4];
                o[0] = (__bf16)fmaf(((float)av[0] - m_) * rr, g4.x, b4.x);
                o[1] = (__bf16)fmaf(((float)av[1] - m_) * rr, g4.y, b4.y);
                o[2] = (__bf16)fmaf(((float)av[2] - m_) * rr, g4.z, b4.z);
                o[3] = (__bf16)fmaf(((float)av[3] - m_) * rr, g4.w, b4.w);
                int off = rq * 128 + ((((qs >> 1) ^ (rq & 7))) << 4) + (qs & 1) * 8;
                *(uint2*)(sB + off) = *(uint2*)o;
            }
        }
        __syncthreads();

        const char* aB = sA + (wr * 64 + lr) * 128;
        const char* bB = sB + (wc * 64 + lr) * 128;
        int swz = (lr & 7) << 4;
        #pragma unroll
        for (int ks = 0; ks < 2; ++ks) {
            int ko = (ks * 64 + lg * 16) ^ swz;
            bf16x8 af[4], bfr[4];
            #pragma unroll
            for (int ff = 0; ff < 4; ++ff) af[ff]  = *(const bf16x8*)(aB + ff * 2048 + ko);
            #pragma unroll
            for (int ff = 0; ff < 4; ++ff) bfr[ff] = *(const bf16x8*)(bB + ff * 2048 + ko);
            #pragma unroll
            for (int fm = 0; fm < 4; ++fm)
                #pragma unroll
                for (int fn = 0; fn < 4; ++fn)
                    acc[fm][fn] = __builtin_amdgcn_mfma_f32_16x16x32_bf16(
                        af[fm], bfr[fn], acc[fm][fn], 0, 0, 0);
        }
        __syncthreads();
    }

    int tcb = t0 + wc * 64 + lr;
    int mrow0 = by * 128 + wr * 64 + lg * 4;

    if constexpr (OMODE == 1) {
        float* tile = (float*)lds;
        #pragma unroll
        for (int fm = 0; fm < 4; ++fm) {
            int R0 = mrow0 + fm * 16;
            int c_ = R0 >> 1;
            int cloc = c_ - by * 64;
            #pragma unroll
            for (int fn = 0; fn < 4; ++fn) {
                f32x4 v = acc[fm][fn];
                float a0 = v[0] + bias[c_],     g0 = v[1] + bias[c_ + 256];
                float a1 = v[2] + bias[c_ + 1], g1 = v[3] + bias[c_ + 257];
                float o0 = a0 * sigm_f(g0), o1 = a1 * sigm_f(g1);
                int tl = wc * 64 + lr + fn * 16;
                *(float2*)&tile[tl * 68 + cloc] = make_float2(o0, o1);
            }
        }
        __syncthreads();
        #pragma unroll
        for (int it = 0; it < 8; ++it) {
            int fid = it * 256 + tid;
            int tl = fid >> 4, fc = (fid & 15) << 2;
            size_t go = (((size_t)(b * TN + t0 + tl)) << 8) + by * 64 + fc;
            float4 v = *(const float4*)&tile[tl * 68 + fc];
            bf16x4 xr = *(const bf16x4*)(resB + go);
            v.x += (float)xr[0]; v.y += (float)xr[1];
            v.z += (float)xr[2]; v.w += (float)xr[3];
            *(float4*)&tile[tl * 68 + fc] = v;
            bf16x4 ov;
            ov[0] = (__bf16)v.x; ov[1] = (__bf16)v.y;
            ov[2] = (__bf16)v.z; ov[3] = (__bf16)v.w;
            *(bf16x4*)(outB + go) = ov;
        }
        __syncthreads();
        if (tid < 128) {
            const float* rowp = &tile[tid * 68];
            float s = 0.f, ss = 0.f;
            #pragma unroll 8
            for (int cc = 0; cc < 64; ++cc) {
                float v = rowp[cc];
                s += v; ss += v * v;
            }
            atomicAdd(&sAcc[b * TN + t0 + tid], s);
            atomicAdd(&ssAcc[b * TN + t0 + tid], ss);
        }
    } else if constexpr (OMODE == 2) {
        float* tile = (float*)lds;
        #pragma unroll
        for (int ht = 0; ht < 2; ++ht) {
            if (wc == ht) {
                #pragma unroll
                for (int fm = 0; fm < 4; ++fm) {
                    int R0 = mrow0 + fm * 16;
                    int mloc = R0 - by * 128;
                    #pragma unroll
                    for (int fn = 0; fn < 4; ++fn) {
                        int t = tcb + fn * 16;
                        f32x4 v = acc[fm][fn];
                        bf16x4 rv = *(const bf16x4*)(resB + (((size_t)(b * TN + t)) << 8) + R0);
                        int tloc = lr + fn * 16;
                        tile[(mloc + 0) * 68 + tloc] = v[0] + bias[R0 + 0] + (float)rv[0];
                        tile[(mloc + 1) * 68 + tloc] = v[1] + bias[R0 + 1] + (float)rv[1];
                        tile[(mloc + 2) * 68 + tloc] = v[2] + bias[R0 + 2] + (float)rv[2];
                        tile[(mloc + 3) * 68 + tloc] = v[3] + bias[R0 + 3] + (float)rv[3];
                    }
                }
            }
            __syncthreads();
            #pragma unroll
            for (int it = 0; it < 8; ++it) {
                int fid = it * 256 + tid;
                int mm = fid >> 4, fc = (fid & 15) << 2;
                float4 v = *(const float4*)&tile[mm * 68 + fc];
                *(float4*)(outF + ((size_t)(b * HN + by * 128 + mm)) * TN + t0 + ht * 64 + fc) = v;
            }
            __syncthreads();
        }
    } else {
        #pragma unroll
        for (int fm = 0; fm < 4; ++fm) {
            int R0 = mrow0 + fm * 16;
            #pragma unroll
            for (int fn = 0; fn < 4; ++fn) {
                int t = tcb + fn * 16;
                f32x4 v = acc[fm][fn];
                size_t rowoff = ((size_t)(b * TN + t)) << 8;
                if constexpr (GLU) {
                    int c_ = R0 >> 1;
                    float a0 = v[0] + bias[c_],     g0 = v[1] + bias[c_ + 256];
                    float a1 = v[2] + bias[c_ + 1], g1 = v[3] + bias[c_ + 257];
                    float o0 = a0 * sigm_f(g0), o1 = a1 * sigm_f(g1);
                    if constexpr (GELUOUT) { o0 = gelu_f(o0); o1 = gelu_f(o1); }
                    bf16x2 ov; ov[0] = (__bf16)o0; ov[1] = (__bf16)o1;
                    *(bf16x2*)(outB + rowoff + c_) = ov;
                } else {
                    float vv[4];
                    #pragma unroll
                    for (int j = 0; j < 4; ++j) vv[j] = v[j] + bias[R0 + j];
                    if constexpr (GELUOUT) {
                        #pragma unroll
                        for (int j = 0; j < 4; ++j) vv[j] = gelu_f(vv[j]);
                    }
                    bf16x4 ov;
                    #pragma unroll
                    for (int j = 0; j < 4; ++j) ov[j] = (__bf16)vv[j];
                    *(bf16x4*)(outB + rowoff + R0) = ov;
                }
            }
        }
    }
}

extern "C" void kernel_launch(void* const* d_in, const int* in_sizes, int n_in,
                              void* d_out, int out_size, void* d_ws, size_t ws_size,
                              hipStream_t stream)
{
    (void)in_sizes; (void)n_in; (void)out_size; (void)ws_size;
    const float* x      = (const float*)d_in[0];
    const float* log_dt = (const float*)d_in[1];
    const float* C_re   = (const float*)d_in[2];
    const float* C_im   = (const float*)d_in[3];
    const float* logAr  = (const float*)d_in[4];
    const float* A_im   = (const float*)d_in[5];
    const float* Dp     = (const float*)d_in[6];
    const float* outW   = (const float*)d_in[7];
    const float* outB   = (const float*)d_in[8];
    const float* ln1g   = (const float*)d_in[9];
    const float* ln1b   = (const float*)d_in[10];
    const float* lin1W  = (const float*)d_in[11];
    const float* lin1b  = (const float*)d_in[12];
    const float* gluW   = (const float*)d_in[13];
    const float* glub   = (const float*)d_in[14];
    const float* ln2g   = (const float*)d_in[15];
    const float* ln2b   = (const float*)d_in[16];
    const float* ff2aW  = (const float*)d_in[17];
    const float* ff2ab  = (const float*)d_in[18];
    const float* ff2bW  = (const float*)d_in[19];
    const float* ff2bb  = (const float*)d_in[20];
    float* out = (float*)d_out;

    char* ws = (char*)d_ws;
    const size_t MB = 1u << 20;
    float*  P    = (float*)(ws);
    float*  mu1  = (float*)(ws + 0x40000);
    float*  rs1  = (float*)(ws + 0x80000);
    float*  mu2  = (float*)(ws + 0xC0000);
    float*  rs2  = (float*)(ws + 0x100000);
    __bf16* WpO  = (__bf16*)(ws + 0x140000);
    __bf16* WpL  = (__bf16*)(ws + 0x180000);
    __bf16* WpG  = (__bf16*)(ws + 0x1A0000);
    __bf16* WpA  = (__bf16*)(ws + 0x220000);
    __bf16* WpB  = (__bf16*)(ws + 0x240000);
    float*  s1   = (float*)(ws + 0x280000);
    float*  ss1  = (float*)(ws + 0x2C0000);
    float*  s2   = (float*)(ws + 0x300000);
    float*  ss2  = (float*)(ws + 0x340000);
    __bf16* x_cl = (__bf16*)(ws + 4 * MB);     // 32MB [B][T][H] bf16
    char*   slB  = ws + 36 * MB;               // 32MB
    char*   slC  = ws + 68 * MB;               // 32MB

    // zero stats accumulators (s1,ss1,s2,ss2 contiguous 1MB)
    hipMemsetAsync(ws + 0x280000, 0, 0x100000, stream);

    prep_kernel<<<64, 64, 0, stream>>>(log_dt, C_re, C_im, logAr, A_im, P);
    prep_w_kernel<<<64, 256, 0, stream>>>(outW,  WpO, 256, 1);
    prep_w_kernel<<<32, 256, 0, stream>>>(lin1W, WpL, 256, 0);
    prep_w_kernel<<<128, 256, 0, stream>>>(gluW, WpG, 512, 1);
    prep_w_kernel<<<32, 256, 0, stream>>>(ff2aW, WpA, 256, 0);
    prep_w_kernel<<<32, 256, 0, stream>>>(ff2bW, WpB, 256, 0);

    // x -> channels-last bf16 + LN1 partial stats, then finalize
    transpose_kernel<float, true><<<dim3(128, 4, BN), 256, 0, stream>>>(x, x_cl, s1, ss1);
    ln_fin_kernel<<<256, 256, 0, stream>>>(s1, ss1, mu1, rs1);

    __bf16* gu_raw = (__bf16*)slC;
    __bf16* gu_cl  = (__bf16*)slB;
    scan_kernel<<<2048, 256, 0, stream>>>(x, mu1, rs1, ln1g, ln1b, Dp, P, gu_raw);
    transpose_kernel<__bf16, false><<<dim3(128, 4, BN), 256, 0, stream>>>(gu_raw, gu_cl,
                                                                          nullptr, nullptr);

    __bf16* y2g = (__bf16*)slC;   // overwrites gu_raw
    __bf16* y3  = (__bf16*)slB;   // overwrites gu_cl
    __bf16* A_bf = (__bf16*)slC;  // overwrites y2g after GEMM2
    __bf16* t1  = (__bf16*)slB;   // overwrites y3 after GEMM3

    // GEMM1: y2g = gelu(GLU(outW · gu + outB))     grid 512*4
    gemm_cl_kernel<256, 4, true, false, false, true, 0><<<2048, 256, 0, stream>>>(
        gu_cl, nullptr, nullptr, WpO, outB, nullptr, nullptr, nullptr, nullptr,
        nullptr, nullptr, nullptr, nullptr, y2g);
    // GEMM2: y3 = lin1 · y2g + lin1b               grid 512*2
    gemm_cl_kernel<256, 2, false, false, false, false, 0><<<1024, 256, 0, stream>>>(
        y2g, nullptr, nullptr, WpL, lin1b, nullptr, nullptr, nullptr, nullptr,
        nullptr, nullptr, nullptr, nullptr, y3);
    // GEMM3: A_bf = x + GLU(gluW · [x_cl; y3] + glub), + LN2 partial stats
    gemm_cl_kernel<512, 4, true, true, false, false, 1><<<2048, 256, 0, stream>>>(
        x_cl, y3, nullptr, WpG, glub, nullptr, nullptr, nullptr, nullptr,
        x_cl, s2, ss2, nullptr, A_bf);
    ln_fin_kernel<<<256, 256, 0, stream>>>(s2, ss2, mu2, rs2);
    // GEMM4: t1 = gelu(ff2a · LN2(A) + ff2ab)
    gemm_cl_kernel<256, 2, false, false, true, true, 0><<<1024, 256, 0, stream>>>(
        nullptr, nullptr, A_bf, WpA, ff2ab, mu2, rs2, ln2g, ln2b,
        nullptr, nullptr, nullptr, nullptr, t1);
    // GEMM5: out = A + ff2b · t1 + ff2bb   (fp32 [B][H][T])
    gemm_cl_kernel<256, 2, false, false, false, false, 2><<<1024, 256, 0, stream>>>(
        t1, nullptr, nullptr, WpB, ff2bb, nullptr, nullptr, nullptr, nullptr,
        A_bf, nullptr, nullptr, out, nullptr);
}

// Round 12
// 347.759 us; speedup vs baseline: 3.2227x; 1.0835x over previous
//
#include <hip/hip_runtime.h>
#include <math.h>

// S4D block, MI355X round 12: round-8 optimum (no setprio) + single merged prep kernel.
// B=8, H=256, T=8192, N=16 complex states.

#define TN 8192
#define HN 256
#define BN 8
#define NS 16

typedef __bf16 bf16x8 __attribute__((ext_vector_type(8)));
typedef __bf16 bf16x4 __attribute__((ext_vector_type(4)));
typedef __bf16 bf16x2 __attribute__((ext_vector_type(2)));
typedef float  f32x4  __attribute__((ext_vector_type(4)));

__device__ __forceinline__ float gelu_f(float v) {
    return 0.5f * v * (1.f + erff(v * 0.70710678118654752440f));
}
__device__ __forceinline__ float sigm_f(float v) {
    return 1.f / (1.f + expf(-v));
}

// ---------------- merged prep: SSM constants + 5 weight images, one launch ----------------
__device__ __forceinline__ void prep_w_body(const float* __restrict__ W,
                                            __bf16* __restrict__ Wp,
                                            int K, int glu, int id)
{
    int nK = K >> 6;
    int c = id >> 10, r = (id >> 3) & 127, s = id & 7;
    int mt = c / nK, kt = c - mt * nK;
    int R = mt * 128 + r;
    int row = glu ? ((R & 1) ? (R >> 1) + 256 : (R >> 1)) : R;
    int k = kt * 64 + ((s ^ (r & 7)) << 3);
    const float* src = W + (size_t)row * K + k;
    __bf16 o[8];
    #pragma unroll
    for (int j = 0; j < 8; ++j) o[j] = (__bf16)src[j];
    *(uint4*)(Wp + (size_t)id * 8) = *(uint4*)o;
}

__global__ __launch_bounds__(256) void prep_all_kernel(
    const float* __restrict__ log_dt, const float* __restrict__ C_re,
    const float* __restrict__ C_im, const float* __restrict__ log_A_real,
    const float* __restrict__ A_imag, float* __restrict__ P,
    const float* __restrict__ outW, __bf16* __restrict__ WpO,
    const float* __restrict__ lin1W, __bf16* __restrict__ WpL,
    const float* __restrict__ gluW, __bf16* __restrict__ WpG,
    const float* __restrict__ ff2aW, __bf16* __restrict__ WpA,
    const float* __restrict__ ff2bW, __bf16* __restrict__ WpB)
{
    int bid = blockIdx.x;
    int tid = threadIdx.x;
    if (bid < 16) {
        int i = bid * 256 + tid;   // 0..4095
        int h = i >> 4;
        float dt = expf(log_dt[h]);
        float Ar = -expf(log_A_real[i]);
        float Ai = A_imag[i];
        float dar = Ar * dt, dai = Ai * dt;
        float er = expf(dar);
        float ar = er * cosf(dai);
        float ai = er * sinf(dai);
        float Er = ar - 1.f, Ei = ai;
        float inv = 1.f / (Ar * Ar + Ai * Ai);
        float Fr = (Er * Ar + Ei * Ai) * inv;
        float Fi = (Ei * Ar - Er * Ai) * inv;
        float cr = C_re[i] * Fr - C_im[i] * Fi;
        float ci = C_re[i] * Fi + C_im[i] * Fr;
        P[i]           = dar;
        P[4096 + i]    = dai;
        P[2*4096 + i]  = 2.f * cr;
        P[3*4096 + i]  = 2.f * ci;
    } else if (bid < 80) {
        prep_w_body(outW,  WpO, 256, 1, (bid - 16) * 256 + tid);
    } else if (bid < 112) {
        prep_w_body(lin1W, WpL, 256, 0, (bid - 80) * 256 + tid);
    } else if (bid < 240) {
        prep_w_body(gluW,  WpG, 512, 1, (bid - 112) * 256 + tid);
    } else if (bid < 272) {
        prep_w_body(ff2aW, WpA, 256, 0, (bid - 240) * 256 + tid);
    } else {
        prep_w_body(ff2bW, WpB, 256, 0, (bid - 272) * 256 + tid);
    }
}

// ---------------- LN stats finalize ----------------
__global__ __launch_bounds__(256) void ln_fin_kernel(const float* __restrict__ s,
                                                     const float* __restrict__ ss,
                                                     float* __restrict__ mu,
                                                     float* __restrict__ rs)
{
    int i = blockIdx.x * 256 + threadIdx.x;   // 0..65535
    float m = s[i] * (1.f / 256.f);
    mu[i] = m;
    rs[i] = rsqrtf(ss[i] * (1.f / 256.f) - m * m + 1e-5f);
}

// ---------------- transpose [B][H][T] (f32 or bf16) -> [B][T][H] bf16, optional LN stats ----------------
template<typename TI, bool STATS>
__global__ __launch_bounds__(256) void transpose_kernel(const TI* __restrict__ in,
                                                        __bf16* __restrict__ out,
                                                        float* __restrict__ sAcc,
                                                        float* __restrict__ ssAcc)
{
    __shared__ float tile[64][65];
    int b = blockIdx.z, h0 = blockIdx.y * 64, t0 = blockIdx.x * 64;
    int tid = threadIdx.x;
    int hl = tid >> 2, pr = tid & 3;
    const TI* src = in + ((size_t)(b * HN + h0 + hl)) * TN + t0 + pr * 16;
    if constexpr (sizeof(TI) == 4) {
        #pragma unroll
        for (int j = 0; j < 4; ++j) {
            float4 v = *(const float4*)((const float*)src + j * 4);
            *(float4*)&tile[hl][pr * 16 + j * 4] = v;
        }
    } else {
        #pragma unroll
        for (int p = 0; p < 2; ++p) {
            bf16x8 v = *(const bf16x8*)((const __bf16*)src + p * 8);
            #pragma unroll
            for (int j = 0; j < 8; ++j) tile[hl][pr * 16 + p * 8 + j] = (float)v[j];
        }
    }
    __syncthreads();
    int tl = tid >> 2;
    __bf16 o[16];
    #pragma unroll
    for (int j = 0; j < 16; ++j) o[j] = (__bf16)tile[pr * 16 + j][tl];
    __bf16* dst = out + ((size_t)(b * TN + t0 + tl)) * HN + h0 + pr * 16;
    *(uint4*)dst = *(uint4*)&o[0];
    *(uint4*)(dst + 8) = *(uint4*)&o[8];
    if constexpr (STATS) {
        if (tid < 64) {
            float s = 0.f, ss = 0.f;
            #pragma unroll 8
            for (int hh = 0; hh < 64; ++hh) {
                float v = tile[hh][tid];
                s += v; ss += v * v;
            }
            atomicAdd(&sAcc[b * TN + t0 + tid], s);
            atomicAdd(&ssAcc[b * TN + t0 + tid], ss);
        }
    }
}

// ---------------- S4D scan (round-8 optimum): 32-elem chunks, 16 states/thread ----------------
__global__ __launch_bounds__(256, 4) void scan_kernel(const float* __restrict__ X,
                                                      const float* __restrict__ mu,
                                                      const float* __restrict__ rs,
                                                      const float* __restrict__ g1,
                                                      const float* __restrict__ b1,
                                                      const float* __restrict__ Dp,
                                                      const float* __restrict__ P,
                                                      __bf16* __restrict__ GU)
{
    __shared__ float ylds[256 * 33];      // 33792B
    __shared__ float astab[16][2];
    __shared__ float c2tab[16][2];
    __shared__ float ksd[7][16][2];       // a^(32*2^k)
    __shared__ float wtot[4][16][2];
    int row = blockIdx.x;
    int b = row >> 8, h = row & 255;
    int tid = threadIdx.x;
    int w = tid >> 6, l = tid & 63;

    float gh = g1[h], bh = b1[h], dh = Dp[h];
    const float* xrow = X + (size_t)(b * HN + h) * TN;
    const float* mup = mu + b * TN;
    const float* rsp = rs + b * TN;

    // ---- tables, spread over 128 threads ----
    if (tid < 112) {
        int k = tid >> 4, n = tid & 15;
        float dar = P[h * NS + n], dai = P[4096 + h * NS + n];
        float m = (float)(32 << k);
        float er = expf(m * dar), ph = m * dai;
        ksd[k][n][0] = er * cosf(ph);
        ksd[k][n][1] = er * sinf(ph);
    } else if (tid < 128) {
        int n = tid & 15;
        float dar = P[h * NS + n], dai = P[4096 + h * NS + n];
        float e1 = expf(dar);
        astab[n][0] = e1 * cosf(dai);
        astab[n][1] = e1 * sinf(dai);
        c2tab[n][0] = P[2*4096 + h * NS + n];
        c2tab[n][1] = P[3*4096 + h * NS + n];
    }

    // ---- stage row + inline LN1 ----
    #pragma unroll 2
    for (int s = 0; s < 8; ++s) {
        int t = (s * 256 + tid) * 4;
        float4 xv = *(const float4*)(xrow + t);
        float4 m4 = *(const float4*)(mup + t);
        float4 r4 = *(const float4*)(rsp + t);
        float* dst = &ylds[(t >> 5) * 33 + (t & 31)];
        dst[0] = fmaf((xv.x - m4.x) * r4.x, gh, bh);
        dst[1] = fmaf((xv.y - m4.y) * r4.y, gh, bh);
        dst[2] = fmaf((xv.z - m4.z) * r4.z, gh, bh);
        dst[3] = fmaf((xv.w - m4.w) * r4.w, gh, bh);
    }
    __syncthreads();

    float ar_[16], ai_[16];
    #pragma unroll
    for (int n = 0; n < 16; ++n) { ar_[n] = astab[n][0]; ai_[n] = astab[n][1]; }

    // ---- pass A: chunk summary ----
    float sr[16], si[16];
    #pragma unroll
    for (int n = 0; n < 16; ++n) { sr[n] = 0.f; si[n] = 0.f; }
    const float* yc = &ylds[tid * 33];
    #pragma unroll 1
    for (int g = 0; g < 4; ++g) {
        float yv[8];
        #pragma unroll
        for (int e = 0; e < 8; ++e) yv[e] = yc[g * 8 + e];
        #pragma unroll
        for (int e = 0; e < 8; ++e) {
            float y = yv[e];
            #pragma unroll
            for (int n = 0; n < 16; ++n) {
                float nr = fmaf(ar_[n], sr[n], fmaf(-ai_[n], si[n], y));
                si[n] = fmaf(ar_[n], si[n], ai_[n] * sr[n]);
                sr[n] = nr;
            }
        }
    }

    // ---- Kogge-Stone over 64 chunks in wave ----
    #pragma unroll
    for (int k = 0; k < 6; ++k) {
        int d = 1 << k;
        #pragma unroll
        for (int n = 0; n < 16; ++n) {
            float qpr = __shfl_up(sr[n], (unsigned)d, 64);
            float qpi = __shfl_up(si[n], (unsigned)d, 64);
            if (l >= d) {
                float pdr = ksd[k][n][0], pdi = ksd[k][n][1];
                sr[n] = fmaf(pdr, qpr, fmaf(-pdi, qpi, sr[n]));
                si[n] = fmaf(pdr, qpi, fmaf(pdi, qpr, si[n]));
            }
        }
    }
    if (l == 63) {
        #pragma unroll
        for (int n = 0; n < 16; ++n) { wtot[w][n][0] = sr[n]; wtot[w][n][1] = si[n]; }
    }
    __syncthreads();

    // ---- s_init per chunk ----
    #pragma unroll
    for (int n = 0; n < 16; ++n) {
        float Lr = __shfl_up(sr[n], 1u, 64);
        float Li = __shfl_up(si[n], 1u, 64);
        if (l == 0) { Lr = 0.f; Li = 0.f; }
        float Sr = 0.f, Si = 0.f;
        float d6r = ksd[6][n][0], d6i = ksd[6][n][1];
        for (int v = 0; v < w; ++v) {
            float tr = fmaf(d6r, Sr, fmaf(-d6i, Si, wtot[v][n][0]));
            float ti = fmaf(d6r, Si, fmaf(d6i, Sr, wtot[v][n][1]));
            Sr = tr; Si = ti;
        }
        float qr = 1.f, qi = 0.f;
        #pragma unroll
        for (int k = 0; k < 6; ++k) {
            if ((l >> k) & 1) {
                float kr = ksd[k][n][0], ki = ksd[k][n][1];
                float t2 = qr * kr - qi * ki;
                qi = fmaf(qr, ki, qi * kr);
                qr = t2;
            }
        }
        sr[n] = fmaf(qr, Sr, fmaf(-qi, Si, Lr));
        si[n] = fmaf(qr, Si, fmaf(qi, Sr, Li));
    }

    float c2r_[16], c2i_[16];
    #pragma unroll
    for (int n = 0; n < 16; ++n) { c2r_[n] = c2tab[n][0]; c2i_[n] = c2tab[n][1]; }

    // ---- pass B: seeded rescan, emit gelu(u) in place ----
    float* yw = &ylds[tid * 33];
    #pragma unroll 1
    for (int g = 0; g < 4; ++g) {
        float yv[8];
        #pragma unroll
        for (int e = 0; e < 8; ++e) yv[e] = yw[g * 8 + e];
        #pragma unroll
        for (int e = 0; e < 8; ++e) {
            float y = yv[e];
            float u = dh * y;
            #pragma unroll
            for (int n = 0; n < 16; ++n) {
                float nr = fmaf(ar_[n], sr[n], fmaf(-ai_[n], si[n], y));
                si[n] = fmaf(ar_[n], si[n], ai_[n] * sr[n]);
                sr[n] = nr;
                u = fmaf(c2r_[n], nr, fmaf(-c2i_[n], si[n], u));
            }
            yw[g * 8 + e] = gelu_f(u);
        }
    }
    __syncthreads();

    // ---- coalesced bf16 write ----
    __bf16* gout = GU + (size_t)(b * HN + h) * TN;
    #pragma unroll 2
    for (int s = 0; s < 8; ++s) {
        int t = (s * 256 + tid) * 4;
        const float* src = &ylds[(t >> 5) * 33 + (t & 31)];
        bf16x4 ov;
        ov[0] = (__bf16)src[0]; ov[1] = (__bf16)src[1];
        ov[2] = (__bf16)src[2]; ov[3] = (__bf16)src[3];
        *(bf16x4*)(gout + t) = ov;
    }
}

// ---------------- MFMA conv1x1 GEMM, channels-last, 1D XCD-swizzled grid ----------------
// OMODE 0: bf16 out [B][T][H]
// OMODE 1: bf16 A [B][T][H] = GLU + bf16 resB, + LN2 partial stats (atomics)
// OMODE 2: fp32 out [B][H][T] += bf16 resB (cl), LDS-transposed store
template<int K, int NTY, bool GLU, bool CONCAT, bool LNIN, bool GELUOUT, int OMODE>
__global__ __launch_bounds__(256) void gemm_cl_kernel(
    const __bf16* __restrict__ B0, const __bf16* __restrict__ B1,
    const __bf16* __restrict__ BA,
    const __bf16* __restrict__ Wp, const float* __restrict__ bias,
    const float* __restrict__ mu, const float* __restrict__ rsd,
    const float* __restrict__ lng, const float* __restrict__ lnb,
    const __bf16* __restrict__ resB,
    float* __restrict__ sAcc, float* __restrict__ ssAcc,
    float* __restrict__ outF, __bf16* __restrict__ outB)
{
    constexpr int nK = K / 64;
    constexpr int LDSSZ = (OMODE != 0) ? 34816 : 32768;
    __shared__ __align__(16) char lds[LDSSZ];
    char* sA = lds;
    char* sB = lds + 16384;
    int tid = threadIdx.x;
    int w = tid >> 6, wr = w >> 1, wc = w & 1;

    int f = blockIdx.x;
    int r8 = f & 7, m = f >> 3;
    int by = m % NTY;
    int c = (m / NTY) * 8 + r8;
    int b = c >> 6;
    int t0 = (c & 63) * 128;

    int lane = tid & 63;
    int lr = tid & 15, lg = (tid >> 4) & 3;
    int rl = lane >> 3, sl = lane & 7;

    f32x4 acc[4][4];
    #pragma unroll
    for (int i = 0; i < 4; ++i)
        #pragma unroll
        for (int j = 0; j < 4; ++j) acc[i][j] = (f32x4){0.f, 0.f, 0.f, 0.f};

    for (int kt = 0; kt < nK; ++kt) {
        {
            const char* asrc = (const char*)Wp + (((size_t)by * nK + kt) << 14)
                               + w * 4096 + lane * 16;
            char* adst = sA + w * 4096;
            #pragma unroll
            for (int i = 0; i < 4; ++i)
                __builtin_amdgcn_global_load_lds(
                    (const __attribute__((address_space(1))) void*)(asrc + i * 1024),
                    (__attribute__((address_space(3))) void*)(adst + i * 1024), 16, 0, 0);
        }
        if constexpr (!LNIN) {
            int kg = kt * 64;
            const __bf16* base = (CONCAT && kg >= 256) ? B1 : B0;
            int kloc = (CONCAT && kg >= 256) ? kg - 256 : kg;
            #pragma unroll
            for (int i = 0; i < 4; ++i) {
                int rb = w * 32 + i * 8 + rl;
                const char* gs = (const char*)(base + (((size_t)(b * TN + t0 + rb)) << 8) + kloc)
                                 + ((sl ^ rl) << 4);
                __builtin_amdgcn_global_load_lds(
                    (const __attribute__((address_space(1))) void*)gs,
                    (__attribute__((address_space(3))) void*)(sB + w * 4096 + i * 1024), 16, 0, 0);
            }
        } else {
            #pragma unroll
            for (int i = 0; i < 8; ++i) {
                int q = i * 256 + tid;
                int rq = q >> 4, qs = q & 15;
                int t = t0 + rq;
                bf16x4 av = *(const bf16x4*)(BA + (((size_t)(b * TN + t)) << 8) + kt * 64 + qs * 4);
                float m_ = mu[b * TN + t], rr = rsd[b * TN + t];
                float4 g4 = *(const float4*)(lng + kt * 64 + qs * 4);
                float4 b4 = *(const float4*)(lnb + kt * 64 + qs * 4);
                __bf16 o[4];
                o[0] = (__bf16)fmaf(((float)av[0] - m_) * rr, g4.x, b4.x);
                o[1] = (__bf16)fmaf(((float)av[1] - m_) * rr, g4.y, b4.y);
                o[2] = (__bf16)fmaf(((float)av[2] - m_) * rr, g4.z, b4.z);
                o[3] = (__bf16)fmaf(((float)av[3] - m_) * rr, g4.w, b4.w);
                int off = rq * 128 + ((((qs >> 1) ^ (rq & 7))) << 4) + (qs & 1) * 8;
                *(uint2*)(sB + off) = *(uint2*)o;
            }
        }
        __syncthreads();

        const char* aB = sA + (wr * 64 + lr) * 128;
        const char* bB = sB + (wc * 64 + lr) * 128;
        int swz = (lr & 7) << 4;
        #pragma unroll
        for (int ks = 0; ks < 2; ++ks) {
            int ko = (ks * 64 + lg * 16) ^ swz;
            bf16x8 af[4], bfr[4];
            #pragma unroll
            for (int ff = 0; ff < 4; ++ff) af[ff]  = *(const bf16x8*)(aB + ff * 2048 + ko);
            #pragma unroll
            for (int ff = 0; ff < 4; ++ff) bfr[ff] = *(const bf16x8*)(bB + ff * 2048 + ko);
            #pragma unroll
            for (int fm = 0; fm < 4; ++fm)
                #pragma unroll
                for (int fn = 0; fn < 4; ++fn)
                    acc[fm][fn] = __builtin_amdgcn_mfma_f32_16x16x32_bf16(
                        af[fm], bfr[fn], acc[fm][fn], 0, 0, 0);
        }
        __syncthreads();
    }

    int tcb = t0 + wc * 64 + lr;
    int mrow0 = by * 128 + wr * 64 + lg * 4;

    if constexpr (OMODE == 1) {
        float* tile = (float*)lds;
        #pragma unroll
        for (int fm = 0; fm < 4; ++fm) {
            int R0 = mrow0 + fm * 16;
            int c_ = R0 >> 1;
            int cloc = c_ - by * 64;
            #pragma unroll
            for (int fn = 0; fn < 4; ++fn) {
                f32x4 v = acc[fm][fn];
                float a0 = v[0] + bias[c_],     g0 = v[1] + bias[c_ + 256];
                float a1 = v[2] + bias[c_ + 1], g1 = v[3] + bias[c_ + 257];
                float o0 = a0 * sigm_f(g0), o1 = a1 * sigm_f(g1);
                int tl = wc * 64 + lr + fn * 16;
                *(float2*)&tile[tl * 68 + cloc] = make_float2(o0, o1);
            }
        }
        __syncthreads();
        #pragma unroll
        for (int it = 0; it < 8; ++it) {
            int fid = it * 256 + tid;
            int tl = fid >> 4, fc = (fid & 15) << 2;
            size_t go = (((size_t)(b * TN + t0 + tl)) << 8) + by * 64 + fc;
            float4 v = *(const float4*)&tile[tl * 68 + fc];
            bf16x4 xr = *(const bf16x4*)(resB + go);
            v.x += (float)xr[0]; v.y += (float)xr[1];
            v.z += (float)xr[2]; v.w += (float)xr[3];
            *(float4*)&tile[tl * 68 + fc] = v;
            bf16x4 ov;
            ov[0] = (__bf16)v.x; ov[1] = (__bf16)v.y;
            ov[2] = (__bf16)v.z; ov[3] = (__bf16)v.w;
            *(bf16x4*)(outB + go) = ov;
        }
        __syncthreads();
        if (tid < 128) {
            const float* rowp = &tile[tid * 68];
            float s = 0.f, ss = 0.f;
            #pragma unroll 8
            for (int cc = 0; cc < 64; ++cc) {
                float v = rowp[cc];
                s += v; ss += v * v;
            }
            atomicAdd(&sAcc[b * TN + t0 + tid], s);
            atomicAdd(&ssAcc[b * TN + t0 + tid], ss);
        }
    } else if constexpr (OMODE == 2) {
        float* tile = (float*)lds;
        #pragma unroll
        for (int ht = 0; ht < 2; ++ht) {
            if (wc == ht) {
                #pragma unroll
                for (int fm = 0; fm < 4; ++fm) {
                    int R0 = mrow0 + fm * 16;
                    int mloc = R0 - by * 128;
                    #pragma unroll
                    for (int fn = 0; fn < 4; ++fn) {
                        int t = tcb + fn * 16;
                        f32x4 v = acc[fm][fn];
                        bf16x4 rv = *(const bf16x4*)(resB + (((size_t)(b * TN + t)) << 8) + R0);
                        int tloc = lr + fn * 16;
                        tile[(mloc + 0) * 68 + tloc] = v[0] + bias[R0 + 0] + (float)rv[0];
                        tile[(mloc + 1) * 68 + tloc] = v[1] + bias[R0 + 1] + (float)rv[1];
                        tile[(mloc + 2) * 68 + tloc] = v[2] + bias[R0 + 2] + (float)rv[2];
                        tile[(mloc + 3) * 68 + tloc] = v[3] + bias[R0 + 3] + (float)rv[3];
                    }
                }
            }
            __syncthreads();
            #pragma unroll
            for (int it = 0; it < 8; ++it) {
                int fid = it * 256 + tid;
                int mm = fid >> 4, fc = (fid & 15) << 2;
                float4 v = *(const float4*)&tile[mm * 68 + fc];
                *(float4*)(outF + ((size_t)(b * HN + by * 128 + mm)) * TN + t0 + ht * 64 + fc) = v;
            }
            __syncthreads();
        }
    } else {
        #pragma unroll
        for (int fm = 0; fm < 4; ++fm) {
            int R0 = mrow0 + fm * 16;
            #pragma unroll
            for (int fn = 0; fn < 4; ++fn) {
                int t = tcb + fn * 16;
                f32x4 v = acc[fm][fn];
                size_t rowoff = ((size_t)(b * TN + t)) << 8;
                if constexpr (GLU) {
                    int c_ = R0 >> 1;
                    float a0 = v[0] + bias[c_],     g0 = v[1] + bias[c_ + 256];
                    float a1 = v[2] + bias[c_ + 1], g1 = v[3] + bias[c_ + 257];
                    float o0 = a0 * sigm_f(g0), o1 = a1 * sigm_f(g1);
                    if constexpr (GELUOUT) { o0 = gelu_f(o0); o1 = gelu_f(o1); }
                    bf16x2 ov; ov[0] = (__bf16)o0; ov[1] = (__bf16)o1;
                    *(bf16x2*)(outB + rowoff + c_) = ov;
                } else {
                    float vv[4];
                    #pragma unroll
                    for (int j = 0; j < 4; ++j) vv[j] = v[j] + bias[R0 + j];
                    if constexpr (GELUOUT) {
                        #pragma unroll
                        for (int j = 0; j < 4; ++j) vv[j] = gelu_f(vv[j]);
                    }
                    bf16x4 ov;
                    #pragma unroll
                    for (int j = 0; j < 4; ++j) ov[j] = (__bf16)vv[j];
                    *(bf16x4*)(outB + rowoff + R0) = ov;
                }
            }
        }
    }
}

extern "C" void kernel_launch(void* const* d_in, const int* in_sizes, int n_in,
                              void* d_out, int out_size, void* d_ws, size_t ws_size,
                              hipStream_t stream)
{
    (void)in_sizes; (void)n_in; (void)out_size; (void)ws_size;
    const float* x      = (const float*)d_in[0];
    const float* log_dt = (const float*)d_in[1];
    const float* C_re   = (const float*)d_in[2];
    const float* C_im   = (const float*)d_in[3];
    const float* logAr  = (const float*)d_in[4];
    const float* A_im   = (const float*)d_in[5];
    const float* Dp     = (const float*)d_in[6];
    const float* outW   = (const float*)d_in[7];
    const float* outB   = (const float*)d_in[8];
    const float* ln1g   = (const float*)d_in[9];
    const float* ln1b   = (const float*)d_in[10];
    const float* lin1W  = (const float*)d_in[11];
    const float* lin1b  = (const float*)d_in[12];
    const float* gluW   = (const float*)d_in[13];
    const float* glub   = (const float*)d_in[14];
    const float* ln2g   = (const float*)d_in[15];
    const float* ln2b   = (const float*)d_in[16];
    const float* ff2aW  = (const float*)d_in[17];
    const float* ff2ab  = (const float*)d_in[18];
    const float* ff2bW  = (const float*)d_in[19];
    const float* ff2bb  = (const float*)d_in[20];
    float* out = (float*)d_out;

    char* ws = (char*)d_ws;
    const size_t MB = 1u << 20;
    float*  P    = (float*)(ws);
    float*  mu1  = (float*)(ws + 0x40000);
    float*  rs1  = (float*)(ws + 0x80000);
    float*  mu2  = (float*)(ws + 0xC0000);
    float*  rs2  = (float*)(ws + 0x100000);
    __bf16* WpO  = (__bf16*)(ws + 0x140000);
    __bf16* WpL  = (__bf16*)(ws + 0x180000);
    __bf16* WpG  = (__bf16*)(ws + 0x1A0000);
    __bf16* WpA  = (__bf16*)(ws + 0x220000);
    __bf16* WpB  = (__bf16*)(ws + 0x240000);
    float*  s1   = (float*)(ws + 0x280000);
    float*  ss1  = (float*)(ws + 0x2C0000);
    float*  s2   = (float*)(ws + 0x300000);
    float*  ss2  = (float*)(ws + 0x340000);
    __bf16* x_cl = (__bf16*)(ws + 4 * MB);     // 32MB [B][T][H] bf16
    char*   slB  = ws + 36 * MB;               // 32MB
    char*   slC  = ws + 68 * MB;               // 32MB

    // zero stats accumulators (s1,ss1,s2,ss2 contiguous 1MB)
    hipMemsetAsync(ws + 0x280000, 0, 0x100000, stream);

    // all constant prep in one launch
    prep_all_kernel<<<304, 256, 0, stream>>>(log_dt, C_re, C_im, logAr, A_im, P,
                                             outW, WpO, lin1W, WpL, gluW, WpG,
                                             ff2aW, WpA, ff2bW, WpB);

    // x -> channels-last bf16 + LN1 partial stats, then finalize
    transpose_kernel<float, true><<<dim3(128, 4, BN), 256, 0, stream>>>(x, x_cl, s1, ss1);
    ln_fin_kernel<<<256, 256, 0, stream>>>(s1, ss1, mu1, rs1);

    __bf16* gu_raw = (__bf16*)slC;
    __bf16* gu_cl  = (__bf16*)slB;
    scan_kernel<<<2048, 256, 0, stream>>>(x, mu1, rs1, ln1g, ln1b, Dp, P, gu_raw);
    transpose_kernel<__bf16, false><<<dim3(128, 4, BN), 256, 0, stream>>>(gu_raw, gu_cl,
                                                                          nullptr, nullptr);

    __bf16* y2g = (__bf16*)slC;   // overwrites gu_raw
    __bf16* y3  = (__bf16*)slB;   // overwrites gu_cl
    __bf16* A_bf = (__bf16*)slC;  // overwrites y2g after GEMM2
    __bf16* t1  = (__bf16*)slB;   // overwrites y3 after GEMM3

    // GEMM1: y2g = gelu(GLU(outW · gu + outB))     grid 512*4
    gemm_cl_kernel<256, 4, true, false, false, true, 0><<<2048, 256, 0, stream>>>(
        gu_cl, nullptr, nullptr, WpO, outB, nullptr, nullptr, nullptr, nullptr,
        nullptr, nullptr, nullptr, nullptr, y2g);
    // GEMM2: y3 = lin1 · y2g + lin1b               grid 512*2
    gemm_cl_kernel<256, 2, false, false, false, false, 0><<<1024, 256, 0, stream>>>(
        y2g, nullptr, nullptr, WpL, lin1b, nullptr, nullptr, nullptr, nullptr,
        nullptr, nullptr, nullptr, nullptr, y3);
    // GEMM3: A_bf = x + GLU(gluW · [x_cl; y3] + glub), + LN2 partial stats
    gemm_cl_kernel<512, 4, true, true, false, false, 1><<<2048, 256, 0, stream>>>(
        x_cl, y3, nullptr, WpG, glub, nullptr, nullptr, nullptr, nullptr,
        x_cl, s2, ss2, nullptr, A_bf);
    ln_fin_kernel<<<256, 256, 0, stream>>>(s2, ss2, mu2, rs2);
    // GEMM4: t1 = gelu(ff2a · LN2(A) + ff2ab)
    gemm_cl_kernel<256, 2, false, false, true, true, 0><<<1024, 256, 0, stream>>>(
        nullptr, nullptr, A_bf, WpA, ff2ab, mu2, rs2, ln2g, ln2b,
        nullptr, nullptr, nullptr, nullptr, t1);
    // GEMM5: out = A + ff2b · t1 + ff2bb   (fp32 [B][H][T])
    gemm_cl_kernel<256, 2, false, false, false, false, 2><<<1024, 256, 0, stream>>>(
        t1, nullptr, nullptr, WpB, ff2bb, nullptr, nullptr, nullptr, nullptr,
        A_bf, nullptr, nullptr, out, nullptr);
}